// Round 2
// baseline (498.690 us; speedup 1.0000x reference)
//
#include <hip/hip_runtime.h>
#include <hip/hip_bf16.h>
#include <math.h>

typedef __bf16 bf16;
typedef __bf16 bf16x8 __attribute__((ext_vector_type(8)));
typedef __bf16 bf16x4 __attribute__((ext_vector_type(4)));
typedef float  f32x4  __attribute__((ext_vector_type(4)));

#define D_MODEL 768
#define MLP_DIM 3072

// ---------------- workspace layout ---------------------------------------------
#define SZ_W1T   ((size_t)8*3072*768*2)        // bf16 [E][N=3072][K=768]
#define SZ_W2T   ((size_t)8*768*3072*2)        // bf16 [E][N=768][K=3072]
#define SZ_XED   ((size_t)8*8*256*768*2)       // bf16 [E][M=2048][768] det
#define SZ_XEC   ((size_t)8*8*32*768*2)        // cls
#define SZ_HD    ((size_t)8*2048*3072*2)       // bf16 [E][M][3072] det
#define SZ_HC    ((size_t)8*256*3072*2)        // cls
#define SZ_YED   ((size_t)8*2048*768*2)        // bf16 fc2 per-slot out det
#define SZ_YEC   ((size_t)8*256*768*2)         // cls
#define SZ_RID   ((size_t)8192*8)
#define SZ_RGD   ((size_t)8192*8)
#define SZ_RIC   ((size_t)1024*8)
#define SZ_RGC   ((size_t)1024*8)
#define SZ_STD   ((size_t)8*8*256*4)           // slot -> token (det)
#define SZ_STC   ((size_t)8*8*32*4)
#define SZ_TSD   ((size_t)2*8192*4)            // token,rank -> global slot (det)
#define SZ_TSC   ((size_t)2*1024*4)

#define OFF_W1T  ((size_t)0)
#define OFF_W2T  (OFF_W1T + SZ_W1T)
#define OFF_XED  (OFF_W2T + SZ_W2T)
#define OFF_XEC  (OFF_XED + SZ_XED)
#define OFF_HD   (OFF_XEC + SZ_XEC)
#define OFF_HC   (OFF_HD  + SZ_HD)
#define OFF_YED  (OFF_HC  + SZ_HC)
#define OFF_YEC  (OFF_YED + SZ_YED)
#define OFF_RID  (OFF_YEC + SZ_YEC)
#define OFF_RGD  (OFF_RID + SZ_RID)
#define OFF_RIC  (OFF_RGD + SZ_RGD)
#define OFF_RGC  (OFF_RIC + SZ_RIC)
#define OFF_STD  (OFF_RGC + SZ_RGC)
#define OFF_STC  (OFF_STD + SZ_STD)
#define OFF_TSD  (OFF_STC + SZ_STC)
#define OFF_TSC  (OFF_TSD + SZ_TSD)

// ---------------- helpers ------------------------------------------------------
__device__ __forceinline__ void lds_load16(const void* g, void* l) {
  __builtin_amdgcn_global_load_lds((__attribute__((address_space(1))) void*)g,
                                   (__attribute__((address_space(3))) void*)l,
                                   16, 0, 0);
}

// tanh-gelu via the exact identity 0.5*(1+tanh(y)) = sigmoid(2y):
// gelu(x) = x * sigmoid(2*0.79788456*(x + 0.044715 x^3)) = x / (1 + exp(z)),
// z = x*(-1.5957691 - 0.07135481*x^2). rcp is the 1-ulp HW approx (output is
// bf16 -> negligible). fminf(z,80) guards exp overflow -> NaN at x < -10.7.
// ~8 VALU vs ~18 for the previous exact-divide version.
__device__ __forceinline__ float gelu_fast(float x) {
  float x2 = x * x;
  float z = x * __builtin_fmaf(-0.07135481627f, x2, -1.5957691216f);
  z = fminf(z, 80.f);
  float e = __expf(z);
  return x * __builtin_amdgcn_rcpf(1.f + e);
}

// ---------------- convt + router merged (independent work, one launch) ---------
// bids [0,2304): router (det 2048 + cls 256, 4 tokens/block);
// bids [2304, 2304+36864): weight transpose fp32 [E][K][N] -> bf16 [E][N][K].
__global__ void convt_router_kernel(const float* __restrict__ w1, bf16* __restrict__ w1t,
                                    const float* __restrict__ w2, bf16* __restrict__ w2t,
                                    const float* __restrict__ xd, const float* __restrict__ wrd,
                                    const float* __restrict__ xc, const float* __restrict__ wrc,
                                    int2* __restrict__ rid, float2* __restrict__ rgd,
                                    int2* __restrict__ ric, float2* __restrict__ rgc) {
  int bid = blockIdx.x;
  if (bid < 2304) {
    // ---- router ----
    const float *x, *wr; int2* ridx; float2* rgate;
    if (bid < 2048) { x = xd; wr = wrd; ridx = rid; rgate = rgd; }
    else { bid -= 2048; x = xc; wr = wrc; ridx = ric; rgate = rgc; }
    int wave = threadIdx.x >> 6;
    int lane = threadIdx.x & 63;
    int t = bid * 4 + wave;
    const float* xr = x + (size_t)t * D_MODEL;
    float acc[8];
#pragma unroll
    for (int e = 0; e < 8; ++e) acc[e] = 0.f;
    for (int d = lane; d < D_MODEL; d += 64) {
      float xv = xr[d];
      const float* w = wr + d * 8;
      float4 a = *(const float4*)w;
      float4 b = *(const float4*)(w + 4);
      acc[0] += xv * a.x; acc[1] += xv * a.y; acc[2] += xv * a.z; acc[3] += xv * a.w;
      acc[4] += xv * b.x; acc[5] += xv * b.y; acc[6] += xv * b.z; acc[7] += xv * b.w;
    }
#pragma unroll
    for (int off = 32; off > 0; off >>= 1) {
#pragma unroll
      for (int e = 0; e < 8; ++e) acc[e] += __shfl_xor(acc[e], off, 64);
    }
    float mx = acc[0];
#pragma unroll
    for (int e = 1; e < 8; ++e) mx = fmaxf(mx, acc[e]);
    float p[8]; float z = 0.f;
#pragma unroll
    for (int e = 0; e < 8; ++e) { p[e] = __expf(acc[e] - mx); z += p[e]; }
    int i1 = 0;
#pragma unroll
    for (int e = 1; e < 8; ++e) if (p[e] > p[i1]) i1 = e;
    int i2 = (i1 == 0) ? 1 : 0;
#pragma unroll
    for (int e = 0; e < 8; ++e) if (e != i1 && p[e] > p[i2]) i2 = e;
    if (lane == 0) {
      float inv = 1.f / z;
      ridx[t]  = make_int2(i1, i2);
      rgate[t] = make_float2(p[i1] * inv, p[i2] * inv);
    }
    return;
  }
  // ---- weight transpose ----
  bid -= 2304;
  __shared__ float tile[32][33];
  const float* src; bf16* dst; int K, N;
  if (bid < 18432) { src = w1; dst = w1t; K = 768; N = 3072; }
  else { bid -= 18432; src = w2; dst = w2t; K = 3072; N = 768; }
  int e = bid / 2304;
  int t = bid - e * 2304;
  int tiles_x = N >> 5;
  int ky = t / tiles_x;
  int n0 = (t - ky * tiles_x) * 32, k0 = ky * 32;
  const float* S_ = src + (size_t)e * K * N;
  bf16* D_ = dst + (size_t)e * K * N;
  int tx = threadIdx.x & 31, ty = threadIdx.x >> 5;
#pragma unroll
  for (int i = 0; i < 4; ++i)
    tile[ty + 8 * i][tx] = S_[(size_t)(k0 + ty + 8 * i) * N + (n0 + tx)];
  __syncthreads();
  int tid = threadIdx.x;
  int n = tid >> 3, kc = (tid & 7) * 4;
  bf16 o[4] = {(bf16)tile[kc][n], (bf16)tile[kc + 1][n], (bf16)tile[kc + 2][n], (bf16)tile[kc + 3][n]};
  *(uint2*)(D_ + (size_t)(n0 + n) * K + (k0 + kc)) = *(const uint2*)o;
}

// ---------------- capacity positions + inverse map (det+cls merged) ------------
// one wave per group; routing preloaded to LDS. Also back-fills empty slots
// with -1 (cnt[e] is wave-uniform) -> no separate memset launch needed.
__global__ void positions_kernel(const int2* __restrict__ rid, int* __restrict__ std_,
                                 int* __restrict__ tsd_, const int2* __restrict__ ric,
                                 int* __restrict__ stc_, int* __restrict__ tsc_) {
  __shared__ int2 sh[1024];
  int bid = blockIdx.x;
  const int2* ridx; int *slot_token, *tok_slot; int S, C, g;
  if (bid < 8) { ridx = rid; slot_token = std_; tok_slot = tsd_; S = 1024; C = 256; g = bid; }
  else { ridx = ric; slot_token = stc_; tok_slot = tsc_; S = 128; C = 32; g = bid - 8; }
  int lane = threadIdx.x;
  int ntok = 8 * S;
  for (int i = lane; i < S; i += 64) sh[i] = ridx[g * S + i];
  __builtin_amdgcn_s_waitcnt(0);   // single wave: no barrier needed
  unsigned long long ltmask = (1ull << lane) - 1ull;
  int cnt[8];
#pragma unroll
  for (int e = 0; e < 8; ++e) cnt[e] = 0;
  int nch = (2 * S) >> 6;
  for (int ch = 0; ch < nch; ++ch) {
    int a = (ch << 6) + lane;
    int r = (a >= S) ? 1 : 0;
    int s = a - r * S;
    int2 id = sh[s];
    int  e  = r ? id.y : id.x;
    unsigned long long mymask = 0;
    int add[8];
#pragma unroll
    for (int ee = 0; ee < 8; ++ee) {
      unsigned long long mk = __ballot(e == ee);
      if (e == ee) mymask = mk;
      add[ee] = __popcll(mk);
    }
    int pos = cnt[e] + __popcll(mymask & ltmask);
    int sl = (e * 8 + g) * C + pos;       // global slot id == e*M + (g*C+pos)
    if (pos < C) slot_token[sl] = s;
    tok_slot[r * ntok + g * S + s] = (pos < C) ? sl : -1;
#pragma unroll
    for (int ee = 0; ee < 8; ++ee) cnt[ee] += add[ee];
  }
  // back-fill unused slots with -1 (replaces the memset kernel)
#pragma unroll
  for (int e = 0; e < 8; ++e) {
    for (int i = cnt[e] + lane; i < C; i += 64)
      slot_token[(e * 8 + g) * C + i] = -1;
  }
}

// ---------------- gather (det+cls merged): 4 slots per block -------------------
__global__ void gather_kernel(const float* __restrict__ xd, const int* __restrict__ std_,
                              bf16* __restrict__ xed, const float* __restrict__ xc,
                              const int* __restrict__ stc_, bf16* __restrict__ xec,
                              int splitd) {
  int bid = blockIdx.x;
  const float* x; const int* slot_token; bf16* xe; int S, C;
  if (bid < splitd) { x = xd; slot_token = std_; xe = xed; S = 1024; C = 256; }
  else { bid -= splitd; x = xc; slot_token = stc_; xe = xec; S = 128; C = 32; }
  int slot = bid * 4 + (threadIdx.x >> 6);
  int lane = threadIdx.x & 63;
  int g = (slot / C) & 7;
  int s = slot_token[slot];
  bf16* dst = xe + (size_t)slot * D_MODEL;
  const float* xr = x + ((size_t)g * S + (s < 0 ? 0 : s)) * D_MODEL;
#pragma unroll
  for (int j = 0; j < 3; ++j) {
    int idx = j * 256 + lane * 4;
    float4 v;
    if (s >= 0) v = *(const float4*)(xr + idx);
    else        v = make_float4(0.f, 0.f, 0.f, 0.f);
    bf16 o[4] = {(bf16)v.x, (bf16)v.y, (bf16)v.z, (bf16)v.w};
    *(uint2*)(dst + idx) = *(const uint2*)o;
  }
}

// ---------------- combine (det+cls merged): 4 tokens per block -----------------
__global__ void combine_kernel(const int* __restrict__ tsd_, const float2* __restrict__ rgd,
                               const bf16* __restrict__ yed, float* __restrict__ outd,
                               const int* __restrict__ tsc_, const float2* __restrict__ rgc,
                               const bf16* __restrict__ yec, float* __restrict__ outc,
                               int splitd) {
  int bid = blockIdx.x;
  const int* tok_slot; const float2* rgate; const bf16* ye; float* out; int ntok;
  if (bid < splitd) { tok_slot = tsd_; rgate = rgd; ye = yed; out = outd; ntok = 8192; }
  else { bid -= splitd; tok_slot = tsc_; rgate = rgc; ye = yec; out = outc; ntok = 1024; }
  int t = bid * 4 + (threadIdx.x >> 6);
  int lane = threadIdx.x & 63;
  int s1 = tok_slot[t];
  int s2 = tok_slot[ntok + t];
  float2 gg = rgate[t];
  float g1 = (s1 < 0) ? 0.f : gg.x;
  float g2 = (s2 < 0) ? 0.f : gg.y;
  const bf16* y1 = ye + (size_t)(s1 < 0 ? 0 : s1) * D_MODEL;
  const bf16* y2 = ye + (size_t)(s2 < 0 ? 0 : s2) * D_MODEL;
  float* orow = out + (size_t)t * D_MODEL;
#pragma unroll
  for (int j = 0; j < 3; ++j) {
    int idx = j * 256 + lane * 4;
    bf16x4 a = *(const bf16x4*)(y1 + idx);
    bf16x4 b = *(const bf16x4*)(y2 + idx);
    float4 o;
    o.x = g1 * (float)a[0] + g2 * (float)b[0];
    o.y = g1 * (float)a[1] + g2 * (float)b[1];
    o.z = g1 * (float)a[2] + g2 * (float)b[2];
    o.w = g1 * (float)a[3] + g2 * (float)b[3];
    *(float4*)(orow + idx) = o;
  }
}

// ---------------- 128x128 bf16 MFMA GEMM, BK=64 collective staging -------------
// Proven 2-barrier structure (R0 baseline, fc1 ~125us, 0 bank conflicts,
// 4 blocks/CU by the 128-reg VGPR+AGPR budget). 8-phase 256^2 port REGRESSED
// (fc1 157us, MfmaUtil 23%): nt=12 can't amortize the pipeline prologue and
// 1 block/CU leaves barrier drains unmasked -- keep the cross-block-overlap
// structure. This round: KT templated (unrolled staging, immediate offsets)
// and cheaper gelu -- attacks the measured VALUBusy 55%.
// Rows are 128B; staging fetches global chunk (c ^ (row&7)) into LDS slot c
// (swizzle on the GLOBAL address -- global_load_lds LDS side is fixed lane*16),
// so fragment b128 reads hit all 8 bank-quads with 2 lanes each (2-way = free).
// det and cls merged into one launch (bid < splitd -> det).
template <int GELU, int KT>
__launch_bounds__(256, 3)
__global__ void gemm_mfma(const bf16* __restrict__ Adet, const bf16* __restrict__ Acls,
                          const bf16* __restrict__ Btall, const float* __restrict__ biasall,
                          int Mdet, int Mcls, int N,
                          int Nmd, int Nmc, int Nn, int minner, int splitd,
                          bf16* __restrict__ Odet, bf16* __restrict__ Ocls) {
  constexpr int K = KT * 64;
  int bid = blockIdx.x;
  const bf16* Aall; bf16* Oall; int M, Nm;
  if (bid < splitd) { Aall = Adet; Oall = Odet; M = Mdet; Nm = Nmd; }
  else { bid -= splitd; Aall = Acls; Oall = Ocls; M = Mcls; Nm = Nmc; }
  const int e   = bid & 7;                 // expert == XCD (blockIdx%8 heuristic)
  const int seq = bid >> 3;
  int m_t, n_t;
  if (minner) { n_t = seq / Nm; m_t = seq - n_t * Nm; }   // fc1: A_e resident in L2
  else        { m_t = seq / Nn; n_t = seq - m_t * Nn; }   // fc2: B_e resident in L2
  const int n0 = n_t * 128;
  const int m0 = m_t * 128;
  const int tid  = threadIdx.x;
  const int wave = tid >> 6, lane = tid & 63;
  const int wm = (wave >> 1) * 64, wn = (wave & 1) * 64;
  const int lrow = lane & 15, lquad = lane >> 4;

  // 32 KB: K-loop A(16KB)|B(16KB); epilogue reuses all 32 KB as 128x128 C-tile
  __shared__ __align__(16) bf16 smem[16384];
  bf16* As = smem;
  bf16* Bs = smem + 8192;

  const bf16* A  = Aall  + (size_t)e * M * K;
  const bf16* Bt = Btall + (size_t)e * N * K;

  // staging: 4 rounds x 32 rows x 8 chunks(16B) per 16KB tile
  const int srow = tid >> 3;                         // 0..31
  const int gq   = (tid & 7) ^ (srow & 7);           // global chunk (swizzled)
  const bf16* Asrc = A  + (size_t)(m0 + srow) * K + gq * 8;
  const bf16* Bsrc = Bt + (size_t)(n0 + srow) * K + gq * 8;
  char* AsB = (char*)As;
  char* BsB = (char*)Bs;
  const int ldsw = wave * 1024;                      // wave-uniform (+lane*16 HW)

  // bias fragment (4 cols per lane)
  const float* bias = biasall + (size_t)e * N;
  float bfr[4];
#pragma unroll
  for (int ni = 0; ni < 4; ++ni) bfr[ni] = bias[n0 + wn + ni * 16 + lrow];

  f32x4 acc[4][4];
#pragma unroll
  for (int mi = 0; mi < 4; ++mi)
#pragma unroll
    for (int ni = 0; ni < 4; ++ni) acc[mi][ni] = {0.f, 0.f, 0.f, 0.f};

  const int xsw = lrow & 7;                          // fragment chunk de-swizzle
  constexpr int UNR = (KT <= 16) ? KT : 4;           // full unroll fc1, 4x fc2
  for (int kt0 = 0; kt0 < KT; kt0 += UNR) {
#pragma unroll
    for (int u = 0; u < UNR; ++u) {
      const int kt = kt0 + u;
      const bf16* a0 = Asrc + kt * 64;
      const bf16* b0 = Bsrc + kt * 64;
#pragma unroll
      for (int rd = 0; rd < 4; ++rd) {
        lds_load16(a0 + (size_t)(rd * 32) * K, AsB + rd * 4096 + ldsw);
        lds_load16(b0 + (size_t)(rd * 32) * K, BsB + rd * 4096 + ldsw);
      }
      __syncthreads();
#pragma unroll
      for (int h = 0; h < 2; ++h) {
        bf16x8 fa[4], fb[4];
        const int ca = ((h * 4 + lquad) ^ xsw) * 8;
#pragma unroll
        for (int i = 0; i < 4; ++i) {
          fa[i] = *(const bf16x8*)(As + (wm + i * 16 + lrow) * 64 + ca);
          fb[i] = *(const bf16x8*)(Bs + (wn + i * 16 + lrow) * 64 + ca);
        }
#pragma unroll
        for (int mi = 0; mi < 4; ++mi)
#pragma unroll
          for (int ni = 0; ni < 4; ++ni)
            acc[mi][ni] = __builtin_amdgcn_mfma_f32_16x16x32_bf16(fa[mi], fb[ni], acc[mi][ni], 0, 0, 0);
      }
      __syncthreads();
    }
  }

  // ---- epilogue: acc -> LDS (swizzled) -> coalesced b128 global stores --------
  // C/D layout: col = lane&15 (+16*ni), row = lquad*4 + r (+16*mi)
#pragma unroll
  for (int mi = 0; mi < 4; ++mi) {
#pragma unroll
    for (int r = 0; r < 4; ++r) {
      int row = wm + mi * 16 + lquad * 4 + r;
#pragma unroll
      for (int ni = 0; ni < 4; ++ni) {
        int colL = wn + ni * 16 + lrow;
        float v = acc[mi][ni][r] + bfr[ni];
        if (GELU) v = gelu_fast(v);
        int chunk = (colL >> 3) ^ (row & 7);           // 16B-chunk swizzle
        smem[row * 128 + chunk * 8 + (colL & 7)] = (bf16)v;
      }
    }
  }
  __syncthreads();
  bf16* O = Oall + (size_t)e * M * N;
#pragma unroll
  for (int it = 0; it < 8; ++it) {
    int idx = it * 256 + tid;          // 0..2047
    int row = idx >> 4;                // 0..127
    int ck  = idx & 15;
    int pchunk = ck ^ (row & 7);
    bf16x8 vv = *(const bf16x8*)(smem + row * 128 + pchunk * 8);
    *(bf16x8*)(O + (size_t)(m0 + row) * N + n0 + ck * 8) = vv;
  }
}

// ---------------- launch -------------------------------------------------------
extern "C" void kernel_launch(void* const* d_in, const int* in_sizes, int n_in,
                              void* d_out, int out_size, void* d_ws, size_t ws_size,
                              hipStream_t stream) {
  (void)in_sizes; (void)n_in; (void)ws_size; (void)out_size;
  const float* x_det  = (const float*)d_in[0];
  const float* x_cls  = (const float*)d_in[1];
  const float* wr_det = (const float*)d_in[2];
  const float* wr_cls = (const float*)d_in[3];
  const float* w1     = (const float*)d_in[4];
  const float* b1     = (const float*)d_in[5];
  const float* w2     = (const float*)d_in[6];
  const float* b2     = (const float*)d_in[7];
  float* out = (float*)d_out;
  char*  ws  = (char*)d_ws;

  bf16*   w1t    = (bf16*)(ws + OFF_W1T);
  bf16*   w2t    = (bf16*)(ws + OFF_W2T);
  bf16*   xe_det = (bf16*)(ws + OFF_XED);
  bf16*   xe_cls = (bf16*)(ws + OFF_XEC);
  bf16*   h_det  = (bf16*)(ws + OFF_HD);
  bf16*   h_cls  = (bf16*)(ws + OFF_HC);
  bf16*   ye_det = (bf16*)(ws + OFF_YED);
  bf16*   ye_cls = (bf16*)(ws + OFF_YEC);
  int2*   ri_det = (int2*)(ws + OFF_RID);
  float2* rg_det = (float2*)(ws + OFF_RGD);
  int2*   ri_cls = (int2*)(ws + OFF_RIC);
  float2* rg_cls = (float2*)(ws + OFF_RGC);
  int*    st_det = (int*)(ws + OFF_STD);
  int*    st_cls = (int*)(ws + OFF_STC);
  int*    ts_det = (int*)(ws + OFF_TSD);
  int*    ts_cls = (int*)(ws + OFF_TSC);

  // weights transpose + routing in one launch (independent; router blocks
  // first, hidden under convt's BW time). memset eliminated: positions_kernel
  // back-fills -1 tails itself.
  convt_router_kernel<<<2304 + 2 * 18432, 256, 0, stream>>>(
      w1, w1t, w2, w2t, x_det, wr_det, x_cls, wr_cls,
      ri_det, rg_det, ri_cls, rg_cls);

  positions_kernel<<<16, 64, 0, stream>>>(ri_det, st_det, ts_det, ri_cls, st_cls, ts_cls);

  // gather to dense expert buffers (det+cls merged)
  gather_kernel<<<4096 + 512, 256, 0, stream>>>(x_det, st_det, xe_det, x_cls, st_cls, xe_cls, 4096);

  // fc1 (det+cls merged): h = gelu(xe @ w1 + b1); n-outer/m-inner (A_e in L2)
  gemm_mfma<1, 12><<<8 * 16 * 24 + 8 * 2 * 24, 256, 0, stream>>>(
      xe_det, xe_cls, w1t, b1, 2048, 256, 3072,
      16, 2, 24, 1, 8 * 16 * 24, h_det, h_cls);

  // fc2 (det+cls merged): ye = h @ w2 + b2; m-outer/n-inner (B_e in L2)
  gemm_mfma<0, 48><<<8 * 16 * 6 + 8 * 2 * 6, 256, 0, stream>>>(
      h_det, h_cls, w2t, b2, 2048, 256, 768,
      16, 2, 6, 0, 8 * 16 * 6, ye_det, ye_cls);

  // combine (det+cls merged): out[t] = sum_r gate_r * ye[slot_r]
  combine_kernel<<<2048 + 256, 256, 0, stream>>>(ts_det, rg_det, ye_det, out,
                                                 ts_cls, rg_cls, ye_cls,
                                                 out + (size_t)8192 * 768, 2048);
}

// Round 3
// 463.032 us; speedup vs baseline: 1.0770x; 1.0770x over previous
//
#include <hip/hip_runtime.h>
#include <hip/hip_bf16.h>
#include <math.h>

typedef __bf16 bf16;
typedef __bf16 bf16x8 __attribute__((ext_vector_type(8)));
typedef __bf16 bf16x4 __attribute__((ext_vector_type(4)));
typedef float  f32x4  __attribute__((ext_vector_type(4)));

#define D_MODEL 768
#define MLP_DIM 3072

// ---------------- workspace layout ---------------------------------------------
#define SZ_W1T   ((size_t)8*3072*768*2)        // bf16 [E][N=3072][K=768]
#define SZ_W2T   ((size_t)8*768*3072*2)        // bf16 [E][N=768][K=3072]
#define SZ_XED   ((size_t)8*8*256*768*2)       // bf16 [E][M=2048][768] det
#define SZ_XEC   ((size_t)8*8*32*768*2)        // cls
#define SZ_HD    ((size_t)8*2048*3072*2)       // bf16 [E][M][3072] det
#define SZ_HC    ((size_t)8*256*3072*2)        // cls
#define SZ_YED   ((size_t)8*2048*768*2)        // bf16 fc2 per-slot out det
#define SZ_YEC   ((size_t)8*256*768*2)         // cls
#define SZ_RID   ((size_t)8192*8)
#define SZ_RGD   ((size_t)8192*8)
#define SZ_RIC   ((size_t)1024*8)
#define SZ_RGC   ((size_t)1024*8)
#define SZ_STD   ((size_t)8*8*256*4)           // slot -> token (det)
#define SZ_STC   ((size_t)8*8*32*4)
#define SZ_TSD   ((size_t)2*8192*4)            // token,rank -> global slot (det)
#define SZ_TSC   ((size_t)2*1024*4)

#define OFF_W1T  ((size_t)0)
#define OFF_W2T  (OFF_W1T + SZ_W1T)
#define OFF_XED  (OFF_W2T + SZ_W2T)
#define OFF_XEC  (OFF_XED + SZ_XED)
#define OFF_HD   (OFF_XEC + SZ_XEC)
#define OFF_HC   (OFF_HD  + SZ_HD)
#define OFF_YED  (OFF_HC  + SZ_HC)
#define OFF_YEC  (OFF_YED + SZ_YED)
#define OFF_RID  (OFF_YEC + SZ_YEC)
#define OFF_RGD  (OFF_RID + SZ_RID)
#define OFF_RIC  (OFF_RGD + SZ_RGD)
#define OFF_RGC  (OFF_RIC + SZ_RIC)
#define OFF_STD  (OFF_RGC + SZ_RGC)
#define OFF_STC  (OFF_STD + SZ_STD)
#define OFF_TSD  (OFF_STC + SZ_STC)
#define OFF_TSC  (OFF_TSD + SZ_TSD)

// ---------------- helpers ------------------------------------------------------
__device__ __forceinline__ void lds_load16(const void* g, void* l) {
  __builtin_amdgcn_global_load_lds((__attribute__((address_space(1))) void*)g,
                                   (__attribute__((address_space(3))) void*)l,
                                   16, 0, 0);
}

// tanh-gelu via the exact identity 0.5*(1+tanh(y)) = sigmoid(2y):
// gelu(x) = x / (1 + exp(z)), z = x*(-1.5957691 - 0.07135481*x^2).
// rcp is the 1-ulp HW approx (output is bf16 -> negligible). fminf(z,80)
// guards exp overflow -> NaN at x < -10.7. ~8 VALU vs ~18 for exact divide.
// Numerics proven in R2 (passed, absmax unchanged).
__device__ __forceinline__ float gelu_fast(float x) {
  float x2 = x * x;
  float z = x * __builtin_fmaf(-0.07135481627f, x2, -1.5957691216f);
  z = fminf(z, 80.f);
  float e = __expf(z);
  return x * __builtin_amdgcn_rcpf(1.f + e);
}

// ---------------- convt + router merged (independent work, one launch) ---------
// bids [0,2304): router (det 2048 + cls 256, 4 tokens/block);
// bids [2304, 2304+36864): weight transpose fp32 [E][K][N] -> bf16 [E][N][K].
__global__ void convt_router_kernel(const float* __restrict__ w1, bf16* __restrict__ w1t,
                                    const float* __restrict__ w2, bf16* __restrict__ w2t,
                                    const float* __restrict__ xd, const float* __restrict__ wrd,
                                    const float* __restrict__ xc, const float* __restrict__ wrc,
                                    int2* __restrict__ rid, float2* __restrict__ rgd,
                                    int2* __restrict__ ric, float2* __restrict__ rgc) {
  int bid = blockIdx.x;
  if (bid < 2304) {
    // ---- router ----
    const float *x, *wr; int2* ridx; float2* rgate;
    if (bid < 2048) { x = xd; wr = wrd; ridx = rid; rgate = rgd; }
    else { bid -= 2048; x = xc; wr = wrc; ridx = ric; rgate = rgc; }
    int wave = threadIdx.x >> 6;
    int lane = threadIdx.x & 63;
    int t = bid * 4 + wave;
    const float* xr = x + (size_t)t * D_MODEL;
    float acc[8];
#pragma unroll
    for (int e = 0; e < 8; ++e) acc[e] = 0.f;
    for (int d = lane; d < D_MODEL; d += 64) {
      float xv = xr[d];
      const float* w = wr + d * 8;
      float4 a = *(const float4*)w;
      float4 b = *(const float4*)(w + 4);
      acc[0] += xv * a.x; acc[1] += xv * a.y; acc[2] += xv * a.z; acc[3] += xv * a.w;
      acc[4] += xv * b.x; acc[5] += xv * b.y; acc[6] += xv * b.z; acc[7] += xv * b.w;
    }
#pragma unroll
    for (int off = 32; off > 0; off >>= 1) {
#pragma unroll
      for (int e = 0; e < 8; ++e) acc[e] += __shfl_xor(acc[e], off, 64);
    }
    float mx = acc[0];
#pragma unroll
    for (int e = 1; e < 8; ++e) mx = fmaxf(mx, acc[e]);
    float p[8]; float z = 0.f;
#pragma unroll
    for (int e = 0; e < 8; ++e) { p[e] = __expf(acc[e] - mx); z += p[e]; }
    int i1 = 0;
#pragma unroll
    for (int e = 1; e < 8; ++e) if (p[e] > p[i1]) i1 = e;
    int i2 = (i1 == 0) ? 1 : 0;
#pragma unroll
    for (int e = 0; e < 8; ++e) if (e != i1 && p[e] > p[i2]) i2 = e;
    if (lane == 0) {
      float inv = 1.f / z;
      ridx[t]  = make_int2(i1, i2);
      rgate[t] = make_float2(p[i1] * inv, p[i2] * inv);
    }
    return;
  }
  // ---- weight transpose ----
  bid -= 2304;
  __shared__ float tile[32][33];
  const float* src; bf16* dst; int K, N;
  if (bid < 18432) { src = w1; dst = w1t; K = 768; N = 3072; }
  else { bid -= 18432; src = w2; dst = w2t; K = 3072; N = 768; }
  int e = bid / 2304;
  int t = bid - e * 2304;
  int tiles_x = N >> 5;
  int ky = t / tiles_x;
  int n0 = (t - ky * tiles_x) * 32, k0 = ky * 32;
  const float* S_ = src + (size_t)e * K * N;
  bf16* D_ = dst + (size_t)e * K * N;
  int tx = threadIdx.x & 31, ty = threadIdx.x >> 5;
#pragma unroll
  for (int i = 0; i < 4; ++i)
    tile[ty + 8 * i][tx] = S_[(size_t)(k0 + ty + 8 * i) * N + (n0 + tx)];
  __syncthreads();
  int tid = threadIdx.x;
  int n = tid >> 3, kc = (tid & 7) * 4;
  bf16 o[4] = {(bf16)tile[kc][n], (bf16)tile[kc + 1][n], (bf16)tile[kc + 2][n], (bf16)tile[kc + 3][n]};
  *(uint2*)(D_ + (size_t)(n0 + n) * K + (k0 + kc)) = *(const uint2*)o;
}

// ---------------- capacity positions + inverse map (det+cls merged) ------------
// one wave per group; routing preloaded to LDS. Also back-fills empty slots
// with -1 (cnt[e] is wave-uniform) -> no separate memset launch needed.
__global__ void positions_kernel(const int2* __restrict__ rid, int* __restrict__ std_,
                                 int* __restrict__ tsd_, const int2* __restrict__ ric,
                                 int* __restrict__ stc_, int* __restrict__ tsc_) {
  __shared__ int2 sh[1024];
  int bid = blockIdx.x;
  const int2* ridx; int *slot_token, *tok_slot; int S, C, g;
  if (bid < 8) { ridx = rid; slot_token = std_; tok_slot = tsd_; S = 1024; C = 256; g = bid; }
  else { ridx = ric; slot_token = stc_; tok_slot = tsc_; S = 128; C = 32; g = bid - 8; }
  int lane = threadIdx.x;
  int ntok = 8 * S;
  for (int i = lane; i < S; i += 64) sh[i] = ridx[g * S + i];
  __builtin_amdgcn_s_waitcnt(0);   // single wave: no barrier needed
  unsigned long long ltmask = (1ull << lane) - 1ull;
  int cnt[8];
#pragma unroll
  for (int e = 0; e < 8; ++e) cnt[e] = 0;
  int nch = (2 * S) >> 6;
  for (int ch = 0; ch < nch; ++ch) {
    int a = (ch << 6) + lane;
    int r = (a >= S) ? 1 : 0;
    int s = a - r * S;
    int2 id = sh[s];
    int  e  = r ? id.y : id.x;
    unsigned long long mymask = 0;
    int add[8];
#pragma unroll
    for (int ee = 0; ee < 8; ++ee) {
      unsigned long long mk = __ballot(e == ee);
      if (e == ee) mymask = mk;
      add[ee] = __popcll(mk);
    }
    int pos = cnt[e] + __popcll(mymask & ltmask);
    int sl = (e * 8 + g) * C + pos;       // global slot id == e*M + (g*C+pos)
    if (pos < C) slot_token[sl] = s;
    tok_slot[r * ntok + g * S + s] = (pos < C) ? sl : -1;
#pragma unroll
    for (int ee = 0; ee < 8; ++ee) cnt[ee] += add[ee];
  }
  // back-fill unused slots with -1 (replaces the memset kernel)
#pragma unroll
  for (int e = 0; e < 8; ++e) {
    for (int i = cnt[e] + lane; i < C; i += 64)
      slot_token[(e * 8 + g) * C + i] = -1;
  }
}

// ---------------- gather (det+cls merged): 4 slots per block -------------------
__global__ void gather_kernel(const float* __restrict__ xd, const int* __restrict__ std_,
                              bf16* __restrict__ xed, const float* __restrict__ xc,
                              const int* __restrict__ stc_, bf16* __restrict__ xec,
                              int splitd) {
  int bid = blockIdx.x;
  const float* x; const int* slot_token; bf16* xe; int S, C;
  if (bid < splitd) { x = xd; slot_token = std_; xe = xed; S = 1024; C = 256; }
  else { bid -= splitd; x = xc; slot_token = stc_; xe = xec; S = 128; C = 32; }
  int slot = bid * 4 + (threadIdx.x >> 6);
  int lane = threadIdx.x & 63;
  int g = (slot / C) & 7;
  int s = slot_token[slot];
  bf16* dst = xe + (size_t)slot * D_MODEL;
  const float* xr = x + ((size_t)g * S + (s < 0 ? 0 : s)) * D_MODEL;
#pragma unroll
  for (int j = 0; j < 3; ++j) {
    int idx = j * 256 + lane * 4;
    float4 v;
    if (s >= 0) v = *(const float4*)(xr + idx);
    else        v = make_float4(0.f, 0.f, 0.f, 0.f);
    bf16 o[4] = {(bf16)v.x, (bf16)v.y, (bf16)v.z, (bf16)v.w};
    *(uint2*)(dst + idx) = *(const uint2*)o;
  }
}

// ---------------- combine (det+cls merged): 4 tokens per block -----------------
__global__ void combine_kernel(const int* __restrict__ tsd_, const float2* __restrict__ rgd,
                               const bf16* __restrict__ yed, float* __restrict__ outd,
                               const int* __restrict__ tsc_, const float2* __restrict__ rgc,
                               const bf16* __restrict__ yec, float* __restrict__ outc,
                               int splitd) {
  int bid = blockIdx.x;
  const int* tok_slot; const float2* rgate; const bf16* ye; float* out; int ntok;
  if (bid < splitd) { tok_slot = tsd_; rgate = rgd; ye = yed; out = outd; ntok = 8192; }
  else { bid -= splitd; tok_slot = tsc_; rgate = rgc; ye = yec; out = outc; ntok = 1024; }
  int t = bid * 4 + (threadIdx.x >> 6);
  int lane = threadIdx.x & 63;
  int s1 = tok_slot[t];
  int s2 = tok_slot[ntok + t];
  float2 gg = rgate[t];
  float g1 = (s1 < 0) ? 0.f : gg.x;
  float g2 = (s2 < 0) ? 0.f : gg.y;
  const bf16* y1 = ye + (size_t)(s1 < 0 ? 0 : s1) * D_MODEL;
  const bf16* y2 = ye + (size_t)(s2 < 0 ? 0 : s2) * D_MODEL;
  float* orow = out + (size_t)t * D_MODEL;
#pragma unroll
  for (int j = 0; j < 3; ++j) {
    int idx = j * 256 + lane * 4;
    bf16x4 a = *(const bf16x4*)(y1 + idx);
    bf16x4 b = *(const bf16x4*)(y2 + idx);
    float4 o;
    o.x = g1 * (float)a[0] + g2 * (float)b[0];
    o.y = g1 * (float)a[1] + g2 * (float)b[1];
    o.z = g1 * (float)a[2] + g2 * (float)b[2];
    o.w = g1 * (float)a[3] + g2 * (float)b[3];
    *(float4*)(orow + idx) = o;
  }
}

// ---------------- 128x128 bf16 MFMA GEMM, BK=64 collective staging -------------
// EXACT R0 structure (runtime K, compact addressing, VGPR=64+64acc, 3 blocks/CU).
// R2's KT-templated unroll raised VGPR 64->72, crossing the 128-total wave
// allocation granule -> occupancy 37->18%, fc2 +10us. The runtime-K loop's
// compact addressing is load-bearing; do not unroll staging addresses.
// Rows are 128B; staging fetches global chunk (c ^ (row&7)) into LDS slot c
// (swizzle on the GLOBAL address -- global_load_lds LDS side is fixed lane*16),
// so fragment b128 reads hit all 8 bank-quads with 2 lanes each (2-way = free).
// det and cls merged into one launch (bid < splitd -> det).
template <int GELU>
__launch_bounds__(256, 3)
__global__ void gemm_mfma(const bf16* __restrict__ Adet, const bf16* __restrict__ Acls,
                          const bf16* __restrict__ Btall, const float* __restrict__ biasall,
                          int Mdet, int Mcls, int N, int K,
                          int Nmd, int Nmc, int Nn, int minner, int splitd,
                          bf16* __restrict__ Odet, bf16* __restrict__ Ocls) {
  int bid = blockIdx.x;
  const bf16* Aall; bf16* Oall; int M, Nm;
  if (bid < splitd) { Aall = Adet; Oall = Odet; M = Mdet; Nm = Nmd; }
  else { bid -= splitd; Aall = Acls; Oall = Ocls; M = Mcls; Nm = Nmc; }
  const int e   = bid & 7;                 // expert == XCD (blockIdx%8 heuristic)
  const int seq = bid >> 3;
  int m_t, n_t;
  if (minner) { n_t = seq / Nm; m_t = seq - n_t * Nm; }   // fc1: A_e resident in L2
  else        { m_t = seq / Nn; n_t = seq - m_t * Nn; }   // fc2: B_e resident in L2
  const int n0 = n_t * 128;
  const int m0 = m_t * 128;
  const int tid  = threadIdx.x;
  const int wave = tid >> 6, lane = tid & 63;
  const int wm = (wave >> 1) * 64, wn = (wave & 1) * 64;
  const int lrow = lane & 15, lquad = lane >> 4;

  // 32 KB: K-loop A(16KB)|B(16KB); epilogue reuses all 32 KB as 128x128 C-tile
  __shared__ __align__(16) bf16 smem[16384];
  bf16* As = smem;
  bf16* Bs = smem + 8192;

  const bf16* A  = Aall  + (size_t)e * M * K;
  const bf16* Bt = Btall + (size_t)e * N * K;

  // staging: 4 rounds x 32 rows x 8 chunks(16B) per 16KB tile
  const int srow = tid >> 3;                         // 0..31
  const int gq   = (tid & 7) ^ (srow & 7);           // global chunk (swizzled)
  const bf16* Asrc = A  + (size_t)(m0 + srow) * K + gq * 8;
  const bf16* Bsrc = Bt + (size_t)(n0 + srow) * K + gq * 8;
  char* AsB = (char*)As;
  char* BsB = (char*)Bs;
  const int ldsw = wave * 1024;                      // wave-uniform (+lane*16 HW)

  // bias fragment (4 cols per lane)
  const float* bias = biasall + (size_t)e * N;
  float bfr[4];
#pragma unroll
  for (int ni = 0; ni < 4; ++ni) bfr[ni] = bias[n0 + wn + ni * 16 + lrow];

  f32x4 acc[4][4];
#pragma unroll
  for (int mi = 0; mi < 4; ++mi)
#pragma unroll
    for (int ni = 0; ni < 4; ++ni) acc[mi][ni] = {0.f, 0.f, 0.f, 0.f};

  const int xsw = lrow & 7;                          // fragment chunk de-swizzle
  const int nsteps = K >> 6;
  for (int kt = 0; kt < nsteps; ++kt) {
    const bf16* a0 = Asrc + kt * 64;
    const bf16* b0 = Bsrc + kt * 64;
#pragma unroll
    for (int rd = 0; rd < 4; ++rd) {
      lds_load16(a0 + (size_t)(rd * 32) * K, AsB + rd * 4096 + ldsw);
      lds_load16(b0 + (size_t)(rd * 32) * K, BsB + rd * 4096 + ldsw);
    }
    __syncthreads();
#pragma unroll
    for (int h = 0; h < 2; ++h) {
      bf16x8 fa[4], fb[4];
      const int ca = ((h * 4 + lquad) ^ xsw) * 8;
#pragma unroll
      for (int i = 0; i < 4; ++i) {
        fa[i] = *(const bf16x8*)(As + (wm + i * 16 + lrow) * 64 + ca);
        fb[i] = *(const bf16x8*)(Bs + (wn + i * 16 + lrow) * 64 + ca);
      }
#pragma unroll
      for (int mi = 0; mi < 4; ++mi)
#pragma unroll
        for (int ni = 0; ni < 4; ++ni)
          acc[mi][ni] = __builtin_amdgcn_mfma_f32_16x16x32_bf16(fa[mi], fb[ni], acc[mi][ni], 0, 0, 0);
    }
    __syncthreads();
  }

  // ---- epilogue: acc -> LDS (swizzled) -> coalesced b128 global stores --------
  // C/D layout: col = lane&15 (+16*ni), row = lquad*4 + r (+16*mi)
#pragma unroll
  for (int mi = 0; mi < 4; ++mi) {
#pragma unroll
    for (int r = 0; r < 4; ++r) {
      int row = wm + mi * 16 + lquad * 4 + r;
#pragma unroll
      for (int ni = 0; ni < 4; ++ni) {
        int colL = wn + ni * 16 + lrow;
        float v = acc[mi][ni][r] + bfr[ni];
        if (GELU) v = gelu_fast(v);
        int chunk = (colL >> 3) ^ (row & 7);           // 16B-chunk swizzle
        smem[row * 128 + chunk * 8 + (colL & 7)] = (bf16)v;
      }
    }
  }
  __syncthreads();
  bf16* O = Oall + (size_t)e * M * N;
#pragma unroll
  for (int it = 0; it < 8; ++it) {
    int idx = it * 256 + tid;          // 0..2047
    int row = idx >> 4;                // 0..127
    int ck  = idx & 15;
    int pchunk = ck ^ (row & 7);
    bf16x8 vv = *(const bf16x8*)(smem + row * 128 + pchunk * 8);
    *(bf16x8*)(O + (size_t)(m0 + row) * N + n0 + ck * 8) = vv;
  }
}

// ---------------- launch -------------------------------------------------------
extern "C" void kernel_launch(void* const* d_in, const int* in_sizes, int n_in,
                              void* d_out, int out_size, void* d_ws, size_t ws_size,
                              hipStream_t stream) {
  (void)in_sizes; (void)n_in; (void)ws_size; (void)out_size;
  const float* x_det  = (const float*)d_in[0];
  const float* x_cls  = (const float*)d_in[1];
  const float* wr_det = (const float*)d_in[2];
  const float* wr_cls = (const float*)d_in[3];
  const float* w1     = (const float*)d_in[4];
  const float* b1     = (const float*)d_in[5];
  const float* w2     = (const float*)d_in[6];
  const float* b2     = (const float*)d_in[7];
  float* out = (float*)d_out;
  char*  ws  = (char*)d_ws;

  bf16*   w1t    = (bf16*)(ws + OFF_W1T);
  bf16*   w2t    = (bf16*)(ws + OFF_W2T);
  bf16*   xe_det = (bf16*)(ws + OFF_XED);
  bf16*   xe_cls = (bf16*)(ws + OFF_XEC);
  bf16*   h_det  = (bf16*)(ws + OFF_HD);
  bf16*   h_cls  = (bf16*)(ws + OFF_HC);
  bf16*   ye_det = (bf16*)(ws + OFF_YED);
  bf16*   ye_cls = (bf16*)(ws + OFF_YEC);
  int2*   ri_det = (int2*)(ws + OFF_RID);
  float2* rg_det = (float2*)(ws + OFF_RGD);
  int2*   ri_cls = (int2*)(ws + OFF_RIC);
  float2* rg_cls = (float2*)(ws + OFF_RGC);
  int*    st_det = (int*)(ws + OFF_STD);
  int*    st_cls = (int*)(ws + OFF_STC);
  int*    ts_det = (int*)(ws + OFF_TSD);
  int*    ts_cls = (int*)(ws + OFF_TSC);

  // weights transpose + routing in one launch (independent; router blocks
  // first, hidden under convt's BW time). memset eliminated: positions_kernel
  // back-fills -1 tails itself.
  convt_router_kernel<<<2304 + 2 * 18432, 256, 0, stream>>>(
      w1, w1t, w2, w2t, x_det, wr_det, x_cls, wr_cls,
      ri_det, rg_det, ri_cls, rg_cls);

  positions_kernel<<<16, 64, 0, stream>>>(ri_det, st_det, ts_det, ri_cls, st_cls, ts_cls);

  // gather to dense expert buffers (det+cls merged)
  gather_kernel<<<4096 + 512, 256, 0, stream>>>(x_det, st_det, xe_det, x_cls, st_cls, xe_cls, 4096);

  // fc1 (det+cls merged): h = gelu(xe @ w1 + b1); n-outer/m-inner (A_e in L2)
  gemm_mfma<1><<<8 * 16 * 24 + 8 * 2 * 24, 256, 0, stream>>>(
      xe_det, xe_cls, w1t, b1, 2048, 256, 3072, 768,
      16, 2, 24, 1, 8 * 16 * 24, h_det, h_cls);

  // fc2 (det+cls merged): ye = h @ w2 + b2; m-outer/n-inner (B_e in L2)
  gemm_mfma<0><<<8 * 16 * 6 + 8 * 2 * 6, 256, 0, stream>>>(
      h_det, h_cls, w2t, b2, 2048, 256, 768, 3072,
      16, 2, 6, 0, 8 * 16 * 6, ye_det, ye_cls);

  // combine (det+cls merged): out[t] = sum_r gate_r * ye[slot_r]
  combine_kernel<<<2048 + 256, 256, 0, stream>>>(ts_det, rg_det, ye_det, out,
                                                 ts_cls, rg_cls, ye_cls,
                                                 out + (size_t)8192 * 768, 2048);
}

// Round 4
// 459.130 us; speedup vs baseline: 1.0862x; 1.0085x over previous
//
#include <hip/hip_runtime.h>
#include <hip/hip_bf16.h>
#include <math.h>

typedef __bf16 bf16;
typedef __bf16 bf16x8 __attribute__((ext_vector_type(8)));
typedef __bf16 bf16x4 __attribute__((ext_vector_type(4)));
typedef float  f32x4  __attribute__((ext_vector_type(4)));

#define D_MODEL 768
#define MLP_DIM 3072

// ---------------- workspace layout ---------------------------------------------
#define SZ_W1T   ((size_t)8*3072*768*2)        // bf16 [E][N=3072][K=768]
#define SZ_W2T   ((size_t)8*768*3072*2)        // bf16 [E][N=768][K=3072]
#define SZ_XED   ((size_t)8*8*256*768*2)       // bf16 [E][M=2048][768] det
#define SZ_XEC   ((size_t)8*8*32*768*2)        // cls
#define SZ_HD    ((size_t)8*2048*3072*2)       // bf16 [E][M][3072] det
#define SZ_HC    ((size_t)8*256*3072*2)        // cls
#define SZ_YED   ((size_t)8*2048*768*2)        // bf16 fc2 per-slot out det
#define SZ_YEC   ((size_t)8*256*768*2)         // cls
#define SZ_RID   ((size_t)8192*8)
#define SZ_RGD   ((size_t)8192*8)
#define SZ_RIC   ((size_t)1024*8)
#define SZ_RGC   ((size_t)1024*8)
#define SZ_STD   ((size_t)8*8*256*4)           // slot -> token (det)
#define SZ_STC   ((size_t)8*8*32*4)
#define SZ_TSD   ((size_t)2*8192*4)            // token,rank -> global slot (det)
#define SZ_TSC   ((size_t)2*1024*4)

#define OFF_W1T  ((size_t)0)
#define OFF_W2T  (OFF_W1T + SZ_W1T)
#define OFF_XED  (OFF_W2T + SZ_W2T)
#define OFF_XEC  (OFF_XED + SZ_XED)
#define OFF_HD   (OFF_XEC + SZ_XEC)
#define OFF_HC   (OFF_HD  + SZ_HD)
#define OFF_YED  (OFF_HC  + SZ_HC)
#define OFF_YEC  (OFF_YED + SZ_YED)
#define OFF_RID  (OFF_YEC + SZ_YEC)
#define OFF_RGD  (OFF_RID + SZ_RID)
#define OFF_RIC  (OFF_RGD + SZ_RGD)
#define OFF_RGC  (OFF_RIC + SZ_RIC)
#define OFF_STD  (OFF_RGC + SZ_RGC)
#define OFF_STC  (OFF_STD + SZ_STD)
#define OFF_TSD  (OFF_STC + SZ_STC)
#define OFF_TSC  (OFF_TSD + SZ_TSD)

// ---------------- helpers ------------------------------------------------------
__device__ __forceinline__ void lds_load16(const void* g, void* l) {
  __builtin_amdgcn_global_load_lds((__attribute__((address_space(1))) void*)g,
                                   (__attribute__((address_space(3))) void*)l,
                                   16, 0, 0);
}

// tanh-gelu via the exact identity 0.5*(1+tanh(y)) = sigmoid(2y):
// gelu(x) = x / (1 + exp(z)), z = x*(-1.5957691 - 0.07135481*x^2).
// No clamp needed: exp overflow -> +inf -> rcp(1+inf)=0 -> gelu->0 (correct
// limit, no NaN path). rcp is the 1-ulp HW approx (output is bf16).
// Numerics proven in R2/R3 (passed, absmax unchanged).
__device__ __forceinline__ float gelu_fast(float x) {
  float x2 = x * x;
  float z = x * __builtin_fmaf(-0.07135481627f, x2, -1.5957691216f);
  float e = __expf(z);
  return x * __builtin_amdgcn_rcpf(1.f + e);
}

// ---------------- convt + router merged (independent work, one launch) ---------
// bids [0,2304): router (det 2048 + cls 256, 4 tokens/block);
// bids [2304, 2304+9216): weight transpose fp32 [E][K][N] -> bf16 [E][N][K],
// 64x64 tiles (R4: was 32x32 / 39168 blocks -- per-block fixed cost and 64B
// write segments held it ~2x over the 227MB/6.3TB/s = 37us floor).
// LDS tile[64][65]: write banks ty+4tx distinct mod 32 (2-way = free); read
// banks kq*65 mod 32 in {0,16} splits 16 n-lanes across halves (2-way = free).
// Output: 4 threads per n-row write 2x bf16x8 each = 128B contiguous segments.
__global__ void convt_router_kernel(const float* __restrict__ w1, bf16* __restrict__ w1t,
                                    const float* __restrict__ w2, bf16* __restrict__ w2t,
                                    const float* __restrict__ xd, const float* __restrict__ wrd,
                                    const float* __restrict__ xc, const float* __restrict__ wrc,
                                    int2* __restrict__ rid, float2* __restrict__ rgd,
                                    int2* __restrict__ ric, float2* __restrict__ rgc) {
  int bid = blockIdx.x;
  if (bid < 2304) {
    // ---- router ----
    const float *x, *wr; int2* ridx; float2* rgate;
    if (bid < 2048) { x = xd; wr = wrd; ridx = rid; rgate = rgd; }
    else { bid -= 2048; x = xc; wr = wrc; ridx = ric; rgate = rgc; }
    int wave = threadIdx.x >> 6;
    int lane = threadIdx.x & 63;
    int t = bid * 4 + wave;
    const float* xr = x + (size_t)t * D_MODEL;
    float acc[8];
#pragma unroll
    for (int e = 0; e < 8; ++e) acc[e] = 0.f;
    for (int d = lane; d < D_MODEL; d += 64) {
      float xv = xr[d];
      const float* w = wr + d * 8;
      float4 a = *(const float4*)w;
      float4 b = *(const float4*)(w + 4);
      acc[0] += xv * a.x; acc[1] += xv * a.y; acc[2] += xv * a.z; acc[3] += xv * a.w;
      acc[4] += xv * b.x; acc[5] += xv * b.y; acc[6] += xv * b.z; acc[7] += xv * b.w;
    }
#pragma unroll
    for (int off = 32; off > 0; off >>= 1) {
#pragma unroll
      for (int e = 0; e < 8; ++e) acc[e] += __shfl_xor(acc[e], off, 64);
    }
    float mx = acc[0];
#pragma unroll
    for (int e = 1; e < 8; ++e) mx = fmaxf(mx, acc[e]);
    float p[8]; float z = 0.f;
#pragma unroll
    for (int e = 0; e < 8; ++e) { p[e] = __expf(acc[e] - mx); z += p[e]; }
    int i1 = 0;
#pragma unroll
    for (int e = 1; e < 8; ++e) if (p[e] > p[i1]) i1 = e;
    int i2 = (i1 == 0) ? 1 : 0;
#pragma unroll
    for (int e = 0; e < 8; ++e) if (e != i1 && p[e] > p[i2]) i2 = e;
    if (lane == 0) {
      float inv = 1.f / z;
      ridx[t]  = make_int2(i1, i2);
      rgate[t] = make_float2(p[i1] * inv, p[i2] * inv);
    }
    return;
  }
  // ---- weight transpose (64x64 tiles) ----
  bid -= 2304;
  __shared__ float tile[64][65];
  const float* src; bf16* dst; int K, N;
  if (bid < 4608) { src = w1; dst = w1t; K = 768; N = 3072; }
  else { bid -= 4608; src = w2; dst = w2t; K = 3072; N = 768; }
  int e = bid / 576;
  int t = bid - e * 576;
  int tiles_x = N >> 6;
  int ky = t / tiles_x;
  int n0 = (t - ky * tiles_x) * 64, k0 = ky * 64;
  const float* S_ = src + (size_t)e * K * N;
  bf16* D_ = dst + (size_t)e * K * N;
  int tx = threadIdx.x & 15, ty = threadIdx.x >> 4;   // 16 x 16
#pragma unroll
  for (int i = 0; i < 4; ++i) {
    float4 v = *(const float4*)(S_ + (size_t)(k0 + ty + i * 16) * N + (n0 + tx * 4));
    int r = ty + i * 16, c = tx * 4;
    tile[r][c] = v.x; tile[r][c + 1] = v.y; tile[r][c + 2] = v.z; tile[r][c + 3] = v.w;
  }
  __syncthreads();
  int n = threadIdx.x >> 2, kq = (threadIdx.x & 3) * 16;
  bf16 o[16];
#pragma unroll
  for (int j = 0; j < 16; ++j) o[j] = (bf16)tile[kq + j][n];
  bf16* drow = D_ + (size_t)(n0 + n) * K + (k0 + kq);
  *(bf16x8*)drow       = *(const bf16x8*)o;
  *(bf16x8*)(drow + 8) = *(const bf16x8*)(o + 8);
}

// ---------------- capacity positions + inverse map (det+cls merged) ------------
// one wave per group; routing preloaded to LDS. Also back-fills empty slots
// with -1 (cnt[e] is wave-uniform) -> no separate memset launch needed.
__global__ void positions_kernel(const int2* __restrict__ rid, int* __restrict__ std_,
                                 int* __restrict__ tsd_, const int2* __restrict__ ric,
                                 int* __restrict__ stc_, int* __restrict__ tsc_) {
  __shared__ int2 sh[1024];
  int bid = blockIdx.x;
  const int2* ridx; int *slot_token, *tok_slot; int S, C, g;
  if (bid < 8) { ridx = rid; slot_token = std_; tok_slot = tsd_; S = 1024; C = 256; g = bid; }
  else { ridx = ric; slot_token = stc_; tok_slot = tsc_; S = 128; C = 32; g = bid - 8; }
  int lane = threadIdx.x;
  int ntok = 8 * S;
  for (int i = lane; i < S; i += 64) sh[i] = ridx[g * S + i];
  __builtin_amdgcn_s_waitcnt(0);   // single wave: no barrier needed
  unsigned long long ltmask = (1ull << lane) - 1ull;
  int cnt[8];
#pragma unroll
  for (int e = 0; e < 8; ++e) cnt[e] = 0;
  int nch = (2 * S) >> 6;
  for (int ch = 0; ch < nch; ++ch) {
    int a = (ch << 6) + lane;
    int r = (a >= S) ? 1 : 0;
    int s = a - r * S;
    int2 id = sh[s];
    int  e  = r ? id.y : id.x;
    unsigned long long mymask = 0;
    int add[8];
#pragma unroll
    for (int ee = 0; ee < 8; ++ee) {
      unsigned long long mk = __ballot(e == ee);
      if (e == ee) mymask = mk;
      add[ee] = __popcll(mk);
    }
    int pos = cnt[e] + __popcll(mymask & ltmask);
    int sl = (e * 8 + g) * C + pos;       // global slot id == e*M + (g*C+pos)
    if (pos < C) slot_token[sl] = s;
    tok_slot[r * ntok + g * S + s] = (pos < C) ? sl : -1;
#pragma unroll
    for (int ee = 0; ee < 8; ++ee) cnt[ee] += add[ee];
  }
  // back-fill unused slots with -1 (replaces the memset kernel)
#pragma unroll
  for (int e = 0; e < 8; ++e) {
    for (int i = cnt[e] + lane; i < C; i += 64)
      slot_token[(e * 8 + g) * C + i] = -1;
  }
}

// ---------------- gather (det+cls merged): 4 slots per block -------------------
__global__ void gather_kernel(const float* __restrict__ xd, const int* __restrict__ std_,
                              bf16* __restrict__ xed, const float* __restrict__ xc,
                              const int* __restrict__ stc_, bf16* __restrict__ xec,
                              int splitd) {
  int bid = blockIdx.x;
  const float* x; const int* slot_token; bf16* xe; int S, C;
  if (bid < splitd) { x = xd; slot_token = std_; xe = xed; S = 1024; C = 256; }
  else { bid -= splitd; x = xc; slot_token = stc_; xe = xec; S = 128; C = 32; }
  int slot = bid * 4 + (threadIdx.x >> 6);
  int lane = threadIdx.x & 63;
  int g = (slot / C) & 7;
  int s = slot_token[slot];
  bf16* dst = xe + (size_t)slot * D_MODEL;
  const float* xr = x + ((size_t)g * S + (s < 0 ? 0 : s)) * D_MODEL;
#pragma unroll
  for (int j = 0; j < 3; ++j) {
    int idx = j * 256 + lane * 4;
    float4 v;
    if (s >= 0) v = *(const float4*)(xr + idx);
    else        v = make_float4(0.f, 0.f, 0.f, 0.f);
    bf16 o[4] = {(bf16)v.x, (bf16)v.y, (bf16)v.z, (bf16)v.w};
    *(uint2*)(dst + idx) = *(const uint2*)o;
  }
}

// ---------------- combine (det+cls merged): 4 tokens per block -----------------
__global__ void combine_kernel(const int* __restrict__ tsd_, const float2* __restrict__ rgd,
                               const bf16* __restrict__ yed, float* __restrict__ outd,
                               const int* __restrict__ tsc_, const float2* __restrict__ rgc,
                               const bf16* __restrict__ yec, float* __restrict__ outc,
                               int splitd) {
  int bid = blockIdx.x;
  const int* tok_slot; const float2* rgate; const bf16* ye; float* out; int ntok;
  if (bid < splitd) { tok_slot = tsd_; rgate = rgd; ye = yed; out = outd; ntok = 8192; }
  else { bid -= splitd; tok_slot = tsc_; rgate = rgc; ye = yec; out = outc; ntok = 1024; }
  int t = bid * 4 + (threadIdx.x >> 6);
  int lane = threadIdx.x & 63;
  int s1 = tok_slot[t];
  int s2 = tok_slot[ntok + t];
  float2 gg = rgate[t];
  float g1 = (s1 < 0) ? 0.f : gg.x;
  float g2 = (s2 < 0) ? 0.f : gg.y;
  const bf16* y1 = ye + (size_t)(s1 < 0 ? 0 : s1) * D_MODEL;
  const bf16* y2 = ye + (size_t)(s2 < 0 ? 0 : s2) * D_MODEL;
  float* orow = out + (size_t)t * D_MODEL;
#pragma unroll
  for (int j = 0; j < 3; ++j) {
    int idx = j * 256 + lane * 4;
    bf16x4 a = *(const bf16x4*)(y1 + idx);
    bf16x4 b = *(const bf16x4*)(y2 + idx);
    float4 o;
    o.x = g1 * (float)a[0] + g2 * (float)b[0];
    o.y = g1 * (float)a[1] + g2 * (float)b[1];
    o.z = g1 * (float)a[2] + g2 * (float)b[2];
    o.w = g1 * (float)a[3] + g2 * (float)b[3];
    *(float4*)(orow + idx) = o;
  }
}

// ---------------- 128x128 bf16 MFMA GEMM, BK=64 collective staging -------------
// EXACT R0 structure (runtime K, compact addressing, VGPR=64+64acc, 3 blocks/CU).
// R2's KT-templated unroll raised VGPR 64->72, crossing the 128-total wave
// allocation granule -> occupancy 37->18%, fc2 +10us. The runtime-K loop's
// compact addressing is load-bearing; do not unroll staging addresses.
// Rows are 128B; staging fetches global chunk (c ^ (row&7)) into LDS slot c
// (swizzle on the GLOBAL address -- global_load_lds LDS side is fixed lane*16),
// so fragment b128 reads hit all 8 bank-quads with 2 lanes each (2-way = free).
// det and cls merged into one launch (bid < splitd -> det).
template <int GELU>
__launch_bounds__(256, 3)
__global__ void gemm_mfma(const bf16* __restrict__ Adet, const bf16* __restrict__ Acls,
                          const bf16* __restrict__ Btall, const float* __restrict__ biasall,
                          int Mdet, int Mcls, int N, int K,
                          int Nmd, int Nmc, int Nn, int minner, int splitd,
                          bf16* __restrict__ Odet, bf16* __restrict__ Ocls) {
  int bid = blockIdx.x;
  const bf16* Aall; bf16* Oall; int M, Nm;
  if (bid < splitd) { Aall = Adet; Oall = Odet; M = Mdet; Nm = Nmd; }
  else { bid -= splitd; Aall = Acls; Oall = Ocls; M = Mcls; Nm = Nmc; }
  const int e   = bid & 7;                 // expert == XCD (blockIdx%8 heuristic)
  const int seq = bid >> 3;
  int m_t, n_t;
  if (minner) { n_t = seq / Nm; m_t = seq - n_t * Nm; }   // fc1: A_e resident in L2
  else        { m_t = seq / Nn; n_t = seq - m_t * Nn; }   // fc2: B_e resident in L2
  const int n0 = n_t * 128;
  const int m0 = m_t * 128;
  const int tid  = threadIdx.x;
  const int wave = tid >> 6, lane = tid & 63;
  const int wm = (wave >> 1) * 64, wn = (wave & 1) * 64;
  const int lrow = lane & 15, lquad = lane >> 4;

  // 32 KB: K-loop A(16KB)|B(16KB); epilogue reuses all 32 KB as 128x128 C-tile
  __shared__ __align__(16) bf16 smem[16384];
  bf16* As = smem;
  bf16* Bs = smem + 8192;

  const bf16* A  = Aall  + (size_t)e * M * K;
  const bf16* Bt = Btall + (size_t)e * N * K;

  // staging: 4 rounds x 32 rows x 8 chunks(16B) per 16KB tile
  const int srow = tid >> 3;                         // 0..31
  const int gq   = (tid & 7) ^ (srow & 7);           // global chunk (swizzled)
  const bf16* Asrc = A  + (size_t)(m0 + srow) * K + gq * 8;
  const bf16* Bsrc = Bt + (size_t)(n0 + srow) * K + gq * 8;
  char* AsB = (char*)As;
  char* BsB = (char*)Bs;
  const int ldsw = wave * 1024;                      // wave-uniform (+lane*16 HW)

  // bias fragment (4 cols per lane)
  const float* bias = biasall + (size_t)e * N;
  float bfr[4];
#pragma unroll
  for (int ni = 0; ni < 4; ++ni) bfr[ni] = bias[n0 + wn + ni * 16 + lrow];

  f32x4 acc[4][4];
#pragma unroll
  for (int mi = 0; mi < 4; ++mi)
#pragma unroll
    for (int ni = 0; ni < 4; ++ni) acc[mi][ni] = {0.f, 0.f, 0.f, 0.f};

  const int xsw = lrow & 7;                          // fragment chunk de-swizzle
  const int nsteps = K >> 6;
  for (int kt = 0; kt < nsteps; ++kt) {
    const bf16* a0 = Asrc + kt * 64;
    const bf16* b0 = Bsrc + kt * 64;
#pragma unroll
    for (int rd = 0; rd < 4; ++rd) {
      lds_load16(a0 + (size_t)(rd * 32) * K, AsB + rd * 4096 + ldsw);
      lds_load16(b0 + (size_t)(rd * 32) * K, BsB + rd * 4096 + ldsw);
    }
    __syncthreads();
#pragma unroll
    for (int h = 0; h < 2; ++h) {
      bf16x8 fa[4], fb[4];
      const int ca = ((h * 4 + lquad) ^ xsw) * 8;
#pragma unroll
      for (int i = 0; i < 4; ++i) {
        fa[i] = *(const bf16x8*)(As + (wm + i * 16 + lrow) * 64 + ca);
        fb[i] = *(const bf16x8*)(Bs + (wn + i * 16 + lrow) * 64 + ca);
      }
#pragma unroll
      for (int mi = 0; mi < 4; ++mi)
#pragma unroll
        for (int ni = 0; ni < 4; ++ni)
          acc[mi][ni] = __builtin_amdgcn_mfma_f32_16x16x32_bf16(fa[mi], fb[ni], acc[mi][ni], 0, 0, 0);
    }
    __syncthreads();
  }

  // ---- epilogue: acc -> LDS (swizzled) -> coalesced b128 global stores --------
  // C/D layout: col = lane&15 (+16*ni), row = lquad*4 + r (+16*mi)
#pragma unroll
  for (int mi = 0; mi < 4; ++mi) {
#pragma unroll
    for (int r = 0; r < 4; ++r) {
      int row = wm + mi * 16 + lquad * 4 + r;
#pragma unroll
      for (int ni = 0; ni < 4; ++ni) {
        int colL = wn + ni * 16 + lrow;
        float v = acc[mi][ni][r] + bfr[ni];
        if (GELU) v = gelu_fast(v);
        int chunk = (colL >> 3) ^ (row & 7);           // 16B-chunk swizzle
        smem[row * 128 + chunk * 8 + (colL & 7)] = (bf16)v;
      }
    }
  }
  __syncthreads();
  bf16* O = Oall + (size_t)e * M * N;
#pragma unroll
  for (int it = 0; it < 8; ++it) {
    int idx = it * 256 + tid;          // 0..2047
    int row = idx >> 4;                // 0..127
    int ck  = idx & 15;
    int pchunk = ck ^ (row & 7);
    bf16x8 vv = *(const bf16x8*)(smem + row * 128 + pchunk * 8);
    *(bf16x8*)(O + (size_t)(m0 + row) * N + n0 + ck * 8) = vv;
  }
}

// ---------------- launch -------------------------------------------------------
extern "C" void kernel_launch(void* const* d_in, const int* in_sizes, int n_in,
                              void* d_out, int out_size, void* d_ws, size_t ws_size,
                              hipStream_t stream) {
  (void)in_sizes; (void)n_in; (void)ws_size; (void)out_size;
  const float* x_det  = (const float*)d_in[0];
  const float* x_cls  = (const float*)d_in[1];
  const float* wr_det = (const float*)d_in[2];
  const float* wr_cls = (const float*)d_in[3];
  const float* w1     = (const float*)d_in[4];
  const float* b1     = (const float*)d_in[5];
  const float* w2     = (const float*)d_in[6];
  const float* b2     = (const float*)d_in[7];
  float* out = (float*)d_out;
  char*  ws  = (char*)d_ws;

  bf16*   w1t    = (bf16*)(ws + OFF_W1T);
  bf16*   w2t    = (bf16*)(ws + OFF_W2T);
  bf16*   xe_det = (bf16*)(ws + OFF_XED);
  bf16*   xe_cls = (bf16*)(ws + OFF_XEC);
  bf16*   h_det  = (bf16*)(ws + OFF_HD);
  bf16*   h_cls  = (bf16*)(ws + OFF_HC);
  bf16*   ye_det = (bf16*)(ws + OFF_YED);
  bf16*   ye_cls = (bf16*)(ws + OFF_YEC);
  int2*   ri_det = (int2*)(ws + OFF_RID);
  float2* rg_det = (float2*)(ws + OFF_RGD);
  int2*   ri_cls = (int2*)(ws + OFF_RIC);
  float2* rg_cls = (float2*)(ws + OFF_RGC);
  int*    st_det = (int*)(ws + OFF_STD);
  int*    st_cls = (int*)(ws + OFF_STC);
  int*    ts_det = (int*)(ws + OFF_TSD);
  int*    ts_cls = (int*)(ws + OFF_TSC);

  // weights transpose (64x64 tiles) + routing in one launch (independent;
  // router blocks first, hidden under convt's BW time). memset eliminated:
  // positions_kernel back-fills -1 tails itself.
  convt_router_kernel<<<2304 + 2 * 4608, 256, 0, stream>>>(
      w1, w1t, w2, w2t, x_det, wr_det, x_cls, wr_cls,
      ri_det, rg_det, ri_cls, rg_cls);

  positions_kernel<<<16, 64, 0, stream>>>(ri_det, st_det, ts_det, ri_cls, st_cls, ts_cls);

  // gather to dense expert buffers (det+cls merged)
  gather_kernel<<<4096 + 512, 256, 0, stream>>>(x_det, st_det, xe_det, x_cls, st_cls, xe_cls, 4096);

  // fc1 (det+cls merged): h = gelu(xe @ w1 + b1); n-outer/m-inner (A_e in L2)
  gemm_mfma<1><<<8 * 16 * 24 + 8 * 2 * 24, 256, 0, stream>>>(
      xe_det, xe_cls, w1t, b1, 2048, 256, 3072, 768,
      16, 2, 24, 1, 8 * 16 * 24, h_det, h_cls);

  // fc2 (det+cls merged): ye = h @ w2 + b2; m-outer/n-inner (B_e in L2)
  gemm_mfma<0><<<8 * 16 * 6 + 8 * 2 * 6, 256, 0, stream>>>(
      h_det, h_cls, w2t, b2, 2048, 256, 768, 3072,
      16, 2, 6, 0, 8 * 16 * 6, ye_det, ye_cls);

  // combine (det+cls merged): out[t] = sum_r gate_r * ye[slot_r]
  combine_kernel<<<2048 + 256, 256, 0, stream>>>(ts_det, rg_det, ye_det, out,
                                                 ts_cls, rg_cls, ye_cls,
                                                 out + (size_t)8192 * 768, 2048);
}

// Round 5
// 436.570 us; speedup vs baseline: 1.1423x; 1.0517x over previous
//
#include <hip/hip_runtime.h>
#include <hip/hip_bf16.h>
#include <math.h>

typedef __bf16 bf16;
typedef __bf16 bf16x8 __attribute__((ext_vector_type(8)));
typedef __bf16 bf16x4 __attribute__((ext_vector_type(4)));
typedef float  f32x4  __attribute__((ext_vector_type(4)));

#define D_MODEL 768
#define MLP_DIM 3072

// ---------------- workspace layout ---------------------------------------------
#define SZ_W1T   ((size_t)8*3072*768*2)        // bf16 [E][N=3072][K=768]
#define SZ_W2T   ((size_t)8*768*3072*2)        // bf16 [E][N=768][K=3072]
#define SZ_XED   ((size_t)8*8*256*768*2)       // bf16 [E][M=2048][768] det
#define SZ_XEC   ((size_t)8*8*32*768*2)        // cls
#define SZ_HD    ((size_t)8*2048*3072*2)       // bf16 [E][M][3072] det
#define SZ_HC    ((size_t)8*256*3072*2)        // cls
#define SZ_YED   ((size_t)8*2048*768*2)        // bf16 fc2 per-slot out det
#define SZ_YEC   ((size_t)8*256*768*2)         // cls
#define SZ_RID   ((size_t)8192*8)
#define SZ_RGD   ((size_t)8192*8)
#define SZ_RIC   ((size_t)1024*8)
#define SZ_RGC   ((size_t)1024*8)
#define SZ_STD   ((size_t)8*8*256*4)           // slot -> token (det)
#define SZ_STC   ((size_t)8*8*32*4)
#define SZ_TSD   ((size_t)2*8192*4)            // token,rank -> global slot (det)
#define SZ_TSC   ((size_t)2*1024*4)

#define OFF_W1T  ((size_t)0)
#define OFF_W2T  (OFF_W1T + SZ_W1T)
#define OFF_XED  (OFF_W2T + SZ_W2T)
#define OFF_XEC  (OFF_XED + SZ_XED)
#define OFF_HD   (OFF_XEC + SZ_XEC)
#define OFF_HC   (OFF_HD  + SZ_HD)
#define OFF_YED  (OFF_HC  + SZ_HC)
#define OFF_YEC  (OFF_YED + SZ_YED)
#define OFF_RID  (OFF_YEC + SZ_YEC)
#define OFF_RGD  (OFF_RID + SZ_RID)
#define OFF_RIC  (OFF_RGD + SZ_RGD)
#define OFF_RGC  (OFF_RIC + SZ_RIC)
#define OFF_STD  (OFF_RGC + SZ_RGC)
#define OFF_STC  (OFF_STD + SZ_STD)
#define OFF_TSD  (OFF_STC + SZ_STC)
#define OFF_TSC  (OFF_TSD + SZ_TSD)

// ---------------- helpers ------------------------------------------------------
__device__ __forceinline__ void lds_load16(const void* g, void* l) {
  __builtin_amdgcn_global_load_lds((__attribute__((address_space(1))) void*)g,
                                   (__attribute__((address_space(3))) void*)l,
                                   16, 0, 0);
}

// tanh-gelu via the exact identity 0.5*(1+tanh(y)) = sigmoid(2y):
// gelu(x) = x / (1 + exp(z)), z = x*(-1.5957691 - 0.07135481*x^2).
// exp overflow -> +inf -> rcp(1+inf)=0 -> gelu->0 (correct limit, no NaN).
__device__ __forceinline__ float gelu_fast(float x) {
  float x2 = x * x;
  float z = x * __builtin_fmaf(-0.07135481627f, x2, -1.5957691216f);
  float e = __expf(z);
  return x * __builtin_amdgcn_rcpf(1.f + e);
}

// ---------------- convt + router merged (independent work, one launch) ---------
// bids [0,2304): router (det 2048 + cls 256, 4 tokens/block);
// bids [2304, 2304+9216): weight transpose fp32 [E][K][N] -> bf16 [E][N][K],
// 64x64 tiles, 128B contiguous write segments (R4).
__global__ void convt_router_kernel(const float* __restrict__ w1, bf16* __restrict__ w1t,
                                    const float* __restrict__ w2, bf16* __restrict__ w2t,
                                    const float* __restrict__ xd, const float* __restrict__ wrd,
                                    const float* __restrict__ xc, const float* __restrict__ wrc,
                                    int2* __restrict__ rid, float2* __restrict__ rgd,
                                    int2* __restrict__ ric, float2* __restrict__ rgc) {
  int bid = blockIdx.x;
  if (bid < 2304) {
    // ---- router ----
    const float *x, *wr; int2* ridx; float2* rgate;
    if (bid < 2048) { x = xd; wr = wrd; ridx = rid; rgate = rgd; }
    else { bid -= 2048; x = xc; wr = wrc; ridx = ric; rgate = rgc; }
    int wave = threadIdx.x >> 6;
    int lane = threadIdx.x & 63;
    int t = bid * 4 + wave;
    const float* xr = x + (size_t)t * D_MODEL;
    float acc[8];
#pragma unroll
    for (int e = 0; e < 8; ++e) acc[e] = 0.f;
    for (int d = lane; d < D_MODEL; d += 64) {
      float xv = xr[d];
      const float* w = wr + d * 8;
      float4 a = *(const float4*)w;
      float4 b = *(const float4*)(w + 4);
      acc[0] += xv * a.x; acc[1] += xv * a.y; acc[2] += xv * a.z; acc[3] += xv * a.w;
      acc[4] += xv * b.x; acc[5] += xv * b.y; acc[6] += xv * b.z; acc[7] += xv * b.w;
    }
#pragma unroll
    for (int off = 32; off > 0; off >>= 1) {
#pragma unroll
      for (int e = 0; e < 8; ++e) acc[e] += __shfl_xor(acc[e], off, 64);
    }
    float mx = acc[0];
#pragma unroll
    for (int e = 1; e < 8; ++e) mx = fmaxf(mx, acc[e]);
    float p[8]; float z = 0.f;
#pragma unroll
    for (int e = 0; e < 8; ++e) { p[e] = __expf(acc[e] - mx); z += p[e]; }
    int i1 = 0;
#pragma unroll
    for (int e = 1; e < 8; ++e) if (p[e] > p[i1]) i1 = e;
    int i2 = (i1 == 0) ? 1 : 0;
#pragma unroll
    for (int e = 0; e < 8; ++e) if (e != i1 && p[e] > p[i2]) i2 = e;
    if (lane == 0) {
      float inv = 1.f / z;
      ridx[t]  = make_int2(i1, i2);
      rgate[t] = make_float2(p[i1] * inv, p[i2] * inv);
    }
    return;
  }
  // ---- weight transpose (64x64 tiles) ----
  bid -= 2304;
  __shared__ float tile[64][65];
  const float* src; bf16* dst; int K, N;
  if (bid < 4608) { src = w1; dst = w1t; K = 768; N = 3072; }
  else { bid -= 4608; src = w2; dst = w2t; K = 3072; N = 768; }
  int e = bid / 576;
  int t = bid - e * 576;
  int tiles_x = N >> 6;
  int ky = t / tiles_x;
  int n0 = (t - ky * tiles_x) * 64, k0 = ky * 64;
  const float* S_ = src + (size_t)e * K * N;
  bf16* D_ = dst + (size_t)e * K * N;
  int tx = threadIdx.x & 15, ty = threadIdx.x >> 4;   // 16 x 16
#pragma unroll
  for (int i = 0; i < 4; ++i) {
    float4 v = *(const float4*)(S_ + (size_t)(k0 + ty + i * 16) * N + (n0 + tx * 4));
    int r = ty + i * 16, c = tx * 4;
    tile[r][c] = v.x; tile[r][c + 1] = v.y; tile[r][c + 2] = v.z; tile[r][c + 3] = v.w;
  }
  __syncthreads();
  int n = threadIdx.x >> 2, kq = (threadIdx.x & 3) * 16;
  bf16 o[16];
#pragma unroll
  for (int j = 0; j < 16; ++j) o[j] = (bf16)tile[kq + j][n];
  bf16* drow = D_ + (size_t)(n0 + n) * K + (k0 + kq);
  *(bf16x8*)drow       = *(const bf16x8*)o;
  *(bf16x8*)(drow + 8) = *(const bf16x8*)(o + 8);
}

// ---------------- capacity positions + inverse map (det+cls merged) ------------
__global__ void positions_kernel(const int2* __restrict__ rid, int* __restrict__ std_,
                                 int* __restrict__ tsd_, const int2* __restrict__ ric,
                                 int* __restrict__ stc_, int* __restrict__ tsc_) {
  __shared__ int2 sh[1024];
  int bid = blockIdx.x;
  const int2* ridx; int *slot_token, *tok_slot; int S, C, g;
  if (bid < 8) { ridx = rid; slot_token = std_; tok_slot = tsd_; S = 1024; C = 256; g = bid; }
  else { ridx = ric; slot_token = stc_; tok_slot = tsc_; S = 128; C = 32; g = bid - 8; }
  int lane = threadIdx.x;
  int ntok = 8 * S;
  for (int i = lane; i < S; i += 64) sh[i] = ridx[g * S + i];
  __builtin_amdgcn_s_waitcnt(0);   // single wave: no barrier needed
  unsigned long long ltmask = (1ull << lane) - 1ull;
  int cnt[8];
#pragma unroll
  for (int e = 0; e < 8; ++e) cnt[e] = 0;
  int nch = (2 * S) >> 6;
  for (int ch = 0; ch < nch; ++ch) {
    int a = (ch << 6) + lane;
    int r = (a >= S) ? 1 : 0;
    int s = a - r * S;
    int2 id = sh[s];
    int  e  = r ? id.y : id.x;
    unsigned long long mymask = 0;
    int add[8];
#pragma unroll
    for (int ee = 0; ee < 8; ++ee) {
      unsigned long long mk = __ballot(e == ee);
      if (e == ee) mymask = mk;
      add[ee] = __popcll(mk);
    }
    int pos = cnt[e] + __popcll(mymask & ltmask);
    int sl = (e * 8 + g) * C + pos;       // global slot id == e*M + (g*C+pos)
    if (pos < C) slot_token[sl] = s;
    tok_slot[r * ntok + g * S + s] = (pos < C) ? sl : -1;
#pragma unroll
    for (int ee = 0; ee < 8; ++ee) cnt[ee] += add[ee];
  }
  // back-fill unused slots with -1 (replaces the memset kernel)
#pragma unroll
  for (int e = 0; e < 8; ++e) {
    for (int i = cnt[e] + lane; i < C; i += 64)
      slot_token[(e * 8 + g) * C + i] = -1;
  }
}

// ---------------- gather (det+cls merged): 4 slots per block -------------------
__global__ void gather_kernel(const float* __restrict__ xd, const int* __restrict__ std_,
                              bf16* __restrict__ xed, const float* __restrict__ xc,
                              const int* __restrict__ stc_, bf16* __restrict__ xec,
                              int splitd) {
  int bid = blockIdx.x;
  const float* x; const int* slot_token; bf16* xe; int S, C;
  if (bid < splitd) { x = xd; slot_token = std_; xe = xed; S = 1024; C = 256; }
  else { bid -= splitd; x = xc; slot_token = stc_; xe = xec; S = 128; C = 32; }
  int slot = bid * 4 + (threadIdx.x >> 6);
  int lane = threadIdx.x & 63;
  int g = (slot / C) & 7;
  int s = slot_token[slot];
  bf16* dst = xe + (size_t)slot * D_MODEL;
  const float* xr = x + ((size_t)g * S + (s < 0 ? 0 : s)) * D_MODEL;
#pragma unroll
  for (int j = 0; j < 3; ++j) {
    int idx = j * 256 + lane * 4;
    float4 v;
    if (s >= 0) v = *(const float4*)(xr + idx);
    else        v = make_float4(0.f, 0.f, 0.f, 0.f);
    bf16 o[4] = {(bf16)v.x, (bf16)v.y, (bf16)v.z, (bf16)v.w};
    *(uint2*)(dst + idx) = *(const uint2*)o;
  }
}

// ---------------- combine (det+cls merged): 4 tokens per block -----------------
__global__ void combine_kernel(const int* __restrict__ tsd_, const float2* __restrict__ rgd,
                               const bf16* __restrict__ yed, float* __restrict__ outd,
                               const int* __restrict__ tsc_, const float2* __restrict__ rgc,
                               const bf16* __restrict__ yec, float* __restrict__ outc,
                               int splitd) {
  int bid = blockIdx.x;
  const int* tok_slot; const float2* rgate; const bf16* ye; float* out; int ntok;
  if (bid < splitd) { tok_slot = tsd_; rgate = rgd; ye = yed; out = outd; ntok = 8192; }
  else { bid -= splitd; tok_slot = tsc_; rgate = rgc; ye = yec; out = outc; ntok = 1024; }
  int t = bid * 4 + (threadIdx.x >> 6);
  int lane = threadIdx.x & 63;
  int s1 = tok_slot[t];
  int s2 = tok_slot[ntok + t];
  float2 gg = rgate[t];
  float g1 = (s1 < 0) ? 0.f : gg.x;
  float g2 = (s2 < 0) ? 0.f : gg.y;
  const bf16* y1 = ye + (size_t)(s1 < 0 ? 0 : s1) * D_MODEL;
  const bf16* y2 = ye + (size_t)(s2 < 0 ? 0 : s2) * D_MODEL;
  float* orow = out + (size_t)t * D_MODEL;
#pragma unroll
  for (int j = 0; j < 3; ++j) {
    int idx = j * 256 + lane * 4;
    bf16x4 a = *(const bf16x4*)(y1 + idx);
    bf16x4 b = *(const bf16x4*)(y2 + idx);
    float4 o;
    o.x = g1 * (float)a[0] + g2 * (float)b[0];
    o.y = g1 * (float)a[1] + g2 * (float)b[1];
    o.z = g1 * (float)a[2] + g2 * (float)b[2];
    o.w = g1 * (float)a[3] + g2 * (float)b[3];
    *(float4*)(orow + idx) = o;
  }
}

// ---------------- 128x128 bf16 MFMA GEMM, BK=64 collective staging -------------
// EXACT R0 structure (runtime K, compact addressing, VGPR=64+64acc, 3 blocks/CU).
// Used for fc1 (nt=12: too few K-steps for the deep pipeline; 3 blocks/CU
// cross-block overlap is the winning mechanism here).
template <int GELU>
__launch_bounds__(256, 3)
__global__ void gemm_mfma(const bf16* __restrict__ Adet, const bf16* __restrict__ Acls,
                          const bf16* __restrict__ Btall, const float* __restrict__ biasall,
                          int Mdet, int Mcls, int N, int K,
                          int Nmd, int Nmc, int Nn, int minner, int splitd,
                          bf16* __restrict__ Odet, bf16* __restrict__ Ocls) {
  int bid = blockIdx.x;
  const bf16* Aall; bf16* Oall; int M, Nm;
  if (bid < splitd) { Aall = Adet; Oall = Odet; M = Mdet; Nm = Nmd; }
  else { bid -= splitd; Aall = Acls; Oall = Ocls; M = Mcls; Nm = Nmc; }
  const int e   = bid & 7;                 // expert == XCD (blockIdx%8 heuristic)
  const int seq = bid >> 3;
  int m_t, n_t;
  if (minner) { n_t = seq / Nm; m_t = seq - n_t * Nm; }   // fc1: A_e resident in L2
  else        { m_t = seq / Nn; n_t = seq - m_t * Nn; }   // fc2: B_e resident in L2
  const int n0 = n_t * 128;
  const int m0 = m_t * 128;
  const int tid  = threadIdx.x;
  const int wave = tid >> 6, lane = tid & 63;
  const int wm = (wave >> 1) * 64, wn = (wave & 1) * 64;
  const int lrow = lane & 15, lquad = lane >> 4;

  // 32 KB: K-loop A(16KB)|B(16KB); epilogue reuses all 32 KB as 128x128 C-tile
  __shared__ __align__(16) bf16 smem[16384];
  bf16* As = smem;
  bf16* Bs = smem + 8192;

  const bf16* A  = Aall  + (size_t)e * M * K;
  const bf16* Bt = Btall + (size_t)e * N * K;

  // staging: 4 rounds x 32 rows x 8 chunks(16B) per 16KB tile
  const int srow = tid >> 3;                         // 0..31
  const int gq   = (tid & 7) ^ (srow & 7);           // global chunk (swizzled)
  const bf16* Asrc = A  + (size_t)(m0 + srow) * K + gq * 8;
  const bf16* Bsrc = Bt + (size_t)(n0 + srow) * K + gq * 8;
  char* AsB = (char*)As;
  char* BsB = (char*)Bs;
  const int ldsw = wave * 1024;                      // wave-uniform (+lane*16 HW)

  // bias fragment (4 cols per lane)
  const float* bias = biasall + (size_t)e * N;
  float bfr[4];
#pragma unroll
  for (int ni = 0; ni < 4; ++ni) bfr[ni] = bias[n0 + wn + ni * 16 + lrow];

  f32x4 acc[4][4];
#pragma unroll
  for (int mi = 0; mi < 4; ++mi)
#pragma unroll
    for (int ni = 0; ni < 4; ++ni) acc[mi][ni] = {0.f, 0.f, 0.f, 0.f};

  const int xsw = lrow & 7;                          // fragment chunk de-swizzle
  const int nsteps = K >> 6;
  for (int kt = 0; kt < nsteps; ++kt) {
    const bf16* a0 = Asrc + kt * 64;
    const bf16* b0 = Bsrc + kt * 64;
#pragma unroll
    for (int rd = 0; rd < 4; ++rd) {
      lds_load16(a0 + (size_t)(rd * 32) * K, AsB + rd * 4096 + ldsw);
      lds_load16(b0 + (size_t)(rd * 32) * K, BsB + rd * 4096 + ldsw);
    }
    __syncthreads();
#pragma unroll
    for (int h = 0; h < 2; ++h) {
      bf16x8 fa[4], fb[4];
      const int ca = ((h * 4 + lquad) ^ xsw) * 8;
#pragma unroll
      for (int i = 0; i < 4; ++i) {
        fa[i] = *(const bf16x8*)(As + (wm + i * 16 + lrow) * 64 + ca);
        fb[i] = *(const bf16x8*)(Bs + (wn + i * 16 + lrow) * 64 + ca);
      }
#pragma unroll
      for (int mi = 0; mi < 4; ++mi)
#pragma unroll
        for (int ni = 0; ni < 4; ++ni)
          acc[mi][ni] = __builtin_amdgcn_mfma_f32_16x16x32_bf16(fa[mi], fb[ni], acc[mi][ni], 0, 0, 0);
    }
    __syncthreads();
  }

  // ---- epilogue: acc -> LDS (swizzled) -> coalesced b128 global stores --------
#pragma unroll
  for (int mi = 0; mi < 4; ++mi) {
#pragma unroll
    for (int r = 0; r < 4; ++r) {
      int row = wm + mi * 16 + lquad * 4 + r;
#pragma unroll
      for (int ni = 0; ni < 4; ++ni) {
        int colL = wn + ni * 16 + lrow;
        float v = acc[mi][ni][r] + bfr[ni];
        if (GELU) v = gelu_fast(v);
        int chunk = (colL >> 3) ^ (row & 7);           // 16B-chunk swizzle
        smem[row * 128 + chunk * 8 + (colL & 7)] = (bf16)v;
      }
    }
  }
  __syncthreads();
  bf16* O = Oall + (size_t)e * M * N;
#pragma unroll
  for (int it = 0; it < 8; ++it) {
    int idx = it * 256 + tid;          // 0..2047
    int row = idx >> 4;                // 0..127
    int ck  = idx & 15;
    int pchunk = ck ^ (row & 7);
    bf16x8 vv = *(const bf16x8*)(smem + row * 128 + pchunk * 8);
    *(bf16x8*)(O + (size_t)(m0 + row) * N + n0 + ck * 8) = vv;
  }
}

// ---------------- 256x256 bf16 MFMA GEMM, 8-phase counted-vmcnt (fc2 only) -----
// R1-proven-correct kernel. R0/R1 subtraction isolates its fc2 effect:
// identical non-GEMM kernels cancel -> dfc2 = dtotal - dfc1 = +2.8 - 31.3 =
// -28.5us. fc2's nt=48 amortizes the 6-stage prologue (fc1's nt=12 can't) and
// its counted vmcnt(4) keeps loads in flight across barriers. fc1 stays 128^2.
template <int GELU>
__launch_bounds__(512, 2)
__global__ void gemm_mfma8p(const bf16* __restrict__ Adet, const bf16* __restrict__ Acls,
                            const bf16* __restrict__ Btall, const float* __restrict__ biasall,
                            int Mdet, int Mcls, int N, int K,
                            int Nmd, int Nmc, int Nn, int minner, int splitd,
                            bf16* __restrict__ Odet, bf16* __restrict__ Ocls) {
  int bid = blockIdx.x;
  const bf16* Aall; bf16* Oall; int M, Nm;
  if (bid < splitd) { Aall = Adet; Oall = Odet; M = Mdet; Nm = Nmd; }
  else { bid -= splitd; Aall = Acls; Oall = Ocls; M = Mcls; Nm = Nmc; }
  const int e   = bid & 7;
  const int seq = bid >> 3;
  int m_t, n_t;
  if (minner) { n_t = seq / Nm; m_t = seq - n_t * Nm; }
  else        { m_t = seq / Nn; n_t = seq - m_t * Nn; }
  const int n0 = n_t * 256;
  const int m0 = m_t * 256;
  const int tid  = threadIdx.x;
  const int wave = tid >> 6, lane = tid & 63;
  const int wm = (wave >> 2) * 128, wn = (wave & 3) * 64;
  const int lrow = lane & 15, lquad = lane >> 4;

  // 128 KB: [buf0|buf1] x [A0|A1|B0|B1] regions of 16KB ([128 rows][64 bf16]).
  __shared__ __align__(16) bf16 smem[65536];
  char* smemB = (char*)smem;

  const bf16* A  = Aall  + (size_t)e * M * K;
  const bf16* Bt = Btall + (size_t)e * N * K;

  const int srow0 = tid >> 3;                        // 0..63
  const int gq    = (tid & 7) ^ (srow0 & 7);
  const bf16* Asrc = A  + (size_t)(m0 + srow0) * K + gq * 8;
  const bf16* Bsrc = Bt + (size_t)(n0 + srow0) * K + gq * 8;
  const int ldsw = wave * 1024;

  const int aBase = (wm ? 8192 : 0) + lrow * 64;
  const int bBase = 16384 + (wn >= 128 ? 8192 : 0) + (wn & 64) * 64 + lrow * 64;
  const int ca0 = (lquad ^ (lrow & 7)) * 8;
  const int ca1 = ca0 ^ 32;

  const float* bias = biasall + (size_t)e * N;
  float bfr[4];
#pragma unroll
  for (int ni = 0; ni < 4; ++ni) bfr[ni] = bias[n0 + wn + ni * 16 + lrow];

  f32x4 acc[8][4];
#pragma unroll
  for (int mi = 0; mi < 8; ++mi)
#pragma unroll
    for (int ni = 0; ni < 4; ++ni) acc[mi][ni] = {0.f, 0.f, 0.f, 0.f};

  bf16x8 fa[2][4], fb0[2][2], fb1[2][2];

#define STG_A(buf, half, kt) do { \
    const bf16* _s = Asrc + (size_t)((half) * 128) * K + (size_t)(kt) * 64; \
    char* _d = smemB + (buf) * 65536 + (half) * 16384 + ldsw; \
    lds_load16(_s, _d); \
    lds_load16(_s + (size_t)64 * K, _d + 8192); \
  } while (0)
#define STG_B(buf, half, kt) do { \
    const bf16* _s = Bsrc + (size_t)((half) * 128) * K + (size_t)(kt) * 64; \
    char* _d = smemB + (buf) * 65536 + 32768 + (half) * 16384 + ldsw; \
    lds_load16(_s, _d); \
    lds_load16(_s + (size_t)64 * K, _d + 8192); \
  } while (0)
#define LDA(buf, qm) do { \
    const bf16* _p = smem + (buf) * 32768 + aBase + (qm) * 4096; \
    _Pragma("unroll") \
    for (int _i = 0; _i < 4; ++_i) { \
      fa[0][_i] = *(const bf16x8*)(_p + _i * 1024 + ca0); \
      fa[1][_i] = *(const bf16x8*)(_p + _i * 1024 + ca1); \
    } \
  } while (0)
#define LDB(buf, qn, FB) do { \
    const bf16* _p = smem + (buf) * 32768 + bBase + (qn) * 2048; \
    _Pragma("unroll") \
    for (int _j = 0; _j < 2; ++_j) { \
      FB[0][_j] = *(const bf16x8*)(_p + _j * 1024 + ca0); \
      FB[1][_j] = *(const bf16x8*)(_p + _j * 1024 + ca1); \
    } \
  } while (0)
#define MM(qm, qn, FB) do { \
    __builtin_amdgcn_s_setprio(1); \
    _Pragma("unroll") \
    for (int _h = 0; _h < 2; ++_h) \
      _Pragma("unroll") \
      for (int _i = 0; _i < 4; ++_i) \
        _Pragma("unroll") \
        for (int _j = 0; _j < 2; ++_j) \
          acc[(qm) * 4 + _i][(qn) * 2 + _j] = __builtin_amdgcn_mfma_f32_16x16x32_bf16( \
              fa[_h][_i], FB[_h][_j], acc[(qm) * 4 + _i][(qn) * 2 + _j], 0, 0, 0); \
    __builtin_amdgcn_s_setprio(0); \
  } while (0)
#define BAR() __builtin_amdgcn_s_barrier()
#define VMC4() asm volatile("s_waitcnt vmcnt(4)" ::: "memory")

  const int nt = K >> 6;          // 48 for fc2; even
  const int niter = nt >> 1;

  // prologue: buf0 <- K0 (4 halves), buf1 <- K1 B-halves; wait buf0 only.
  STG_B(0, 0, 0); STG_B(0, 1, 0); STG_A(0, 0, 0); STG_A(0, 1, 0);
  STG_B(1, 0, 1); STG_B(1, 1, 1);
  VMC4();
  BAR();

  for (int it = 0; it < niter; ++it) {
    const int k1 = 2 * it + 1;
    const int k2 = (2 * it + 2 < nt) ? 2 * it + 2 : nt - 1;   // clamp tail
    const int k3 = (2 * it + 3 < nt) ? 2 * it + 3 : nt - 1;
    // ---- K-tile 2it (buf0) ----
    LDA(0, 0); LDB(0, 0, fb0); STG_A(1, 0, k1); BAR(); MM(0, 0, fb0); BAR();  // P1
    LDB(0, 1, fb1);            STG_A(1, 1, k1); BAR(); MM(0, 1, fb1); BAR();  // P2
    LDA(0, 1);                 STG_B(0, 0, k2); BAR(); MM(1, 1, fb1); BAR();  // P3
                               STG_B(0, 1, k2); VMC4();
                                                BAR(); MM(1, 0, fb0); BAR();  // P4
    // ---- K-tile 2it+1 (buf1) ----
    LDA(1, 0); LDB(1, 0, fb0); STG_A(0, 0, k2); BAR(); MM(0, 0, fb0); BAR();  // P5
    LDB(1, 1, fb1);            STG_A(0, 1, k2); BAR(); MM(0, 1, fb1); BAR();  // P6
    LDA(1, 1);                 STG_B(1, 0, k3); BAR(); MM(1, 1, fb1); BAR();  // P7
                               STG_B(1, 1, k3); VMC4();
                                                BAR(); MM(1, 0, fb0); BAR();  // P8
  }

#undef STG_A
#undef STG_B
#undef LDA
#undef LDB
#undef MM
#undef BAR
#undef VMC4

  // ---- epilogue: acc -> LDS (swizzled 256x256 C-tile) -> coalesced b128 stores
  __syncthreads();   // drains leftover tail stages before smem reuse
#pragma unroll
  for (int mi = 0; mi < 8; ++mi) {
#pragma unroll
    for (int r = 0; r < 4; ++r) {
      int row = wm + mi * 16 + lquad * 4 + r;
#pragma unroll
      for (int ni = 0; ni < 4; ++ni) {
        int colL = wn + ni * 16 + lrow;
        float v = acc[mi][ni][r] + bfr[ni];
        if (GELU) v = gelu_fast(v);
        int chunk = (colL >> 3) ^ (row & 7);           // 16B-chunk swizzle
        smem[row * 256 + chunk * 8 + (colL & 7)] = (bf16)v;
      }
    }
  }
  __syncthreads();
  bf16* O = Oall + (size_t)e * M * N;
#pragma unroll
  for (int itw = 0; itw < 16; ++itw) {
    int idx = itw * 512 + tid;         // 0..8191
    int row = idx >> 5;                // 0..255
    int ck  = idx & 31;
    int pchunk = ck ^ (row & 7);
    bf16x8 vv = *(const bf16x8*)(smem + row * 256 + pchunk * 8);
    *(bf16x8*)(O + (size_t)(m0 + row) * N + n0 + ck * 8) = vv;
  }
}

// ---------------- launch -------------------------------------------------------
extern "C" void kernel_launch(void* const* d_in, const int* in_sizes, int n_in,
                              void* d_out, int out_size, void* d_ws, size_t ws_size,
                              hipStream_t stream) {
  (void)in_sizes; (void)n_in; (void)ws_size; (void)out_size;
  const float* x_det  = (const float*)d_in[0];
  const float* x_cls  = (const float*)d_in[1];
  const float* wr_det = (const float*)d_in[2];
  const float* wr_cls = (const float*)d_in[3];
  const float* w1     = (const float*)d_in[4];
  const float* b1     = (const float*)d_in[5];
  const float* w2     = (const float*)d_in[6];
  const float* b2     = (const float*)d_in[7];
  float* out = (float*)d_out;
  char*  ws  = (char*)d_ws;

  bf16*   w1t    = (bf16*)(ws + OFF_W1T);
  bf16*   w2t    = (bf16*)(ws + OFF_W2T);
  bf16*   xe_det = (bf16*)(ws + OFF_XED);
  bf16*   xe_cls = (bf16*)(ws + OFF_XEC);
  bf16*   h_det  = (bf16*)(ws + OFF_HD);
  bf16*   h_cls  = (bf16*)(ws + OFF_HC);
  bf16*   ye_det = (bf16*)(ws + OFF_YED);
  bf16*   ye_cls = (bf16*)(ws + OFF_YEC);
  int2*   ri_det = (int2*)(ws + OFF_RID);
  float2* rg_det = (float2*)(ws + OFF_RGD);
  int2*   ri_cls = (int2*)(ws + OFF_RIC);
  float2* rg_cls = (float2*)(ws + OFF_RGC);
  int*    st_det = (int*)(ws + OFF_STD);
  int*    st_cls = (int*)(ws + OFF_STC);
  int*    ts_det = (int*)(ws + OFF_TSD);
  int*    ts_cls = (int*)(ws + OFF_TSC);

  // weights transpose (64x64 tiles) + routing in one launch
  convt_router_kernel<<<2304 + 2 * 4608, 256, 0, stream>>>(
      w1, w1t, w2, w2t, x_det, wr_det, x_cls, wr_cls,
      ri_det, rg_det, ri_cls, rg_cls);

  positions_kernel<<<16, 64, 0, stream>>>(ri_det, st_det, ts_det, ri_cls, st_cls, ts_cls);

  // gather to dense expert buffers (det+cls merged)
  gather_kernel<<<4096 + 512, 256, 0, stream>>>(x_det, st_det, xe_det, x_cls, st_cls, xe_cls, 4096);

  // fc1 (det+cls merged): h = gelu(xe @ w1 + b1); 128^2 2-barrier (nt=12)
  gemm_mfma<1><<<8 * 16 * 24 + 8 * 2 * 24, 256, 0, stream>>>(
      xe_det, xe_cls, w1t, b1, 2048, 256, 3072, 768,
      16, 2, 24, 1, 8 * 16 * 24, h_det, h_cls);

  // fc2 (det+cls merged): ye = h @ w2 + b2; 256^2 8-phase (nt=48)
  gemm_mfma8p<0><<<8 * 8 * 3 + 8 * 1 * 3, 512, 0, stream>>>(
      h_det, h_cls, w2t, b2, 2048, 256, 768, 3072,
      8, 1, 3, 0, 8 * 8 * 3, ye_det, ye_cls);

  // combine (det+cls merged): out[t] = sum_r gate_r * ye[slot_r]
  combine_kernel<<<2048 + 256, 256, 0, stream>>>(ts_det, rg_det, ye_det, out,
                                                 ts_cls, rg_cls, ye_cls,
                                                 out + (size_t)8192 * 768, 2048);
}

// Round 6
// 421.181 us; speedup vs baseline: 1.1840x; 1.0365x over previous
//
#include <hip/hip_runtime.h>
#include <hip/hip_bf16.h>
#include <math.h>

typedef __bf16 bf16;
typedef __bf16 bf16x8 __attribute__((ext_vector_type(8)));
typedef __bf16 bf16x4 __attribute__((ext_vector_type(4)));
typedef float  f32x4  __attribute__((ext_vector_type(4)));

#define D_MODEL 768
#define MLP_DIM 3072

// ---------------- workspace layout ---------------------------------------------
#define SZ_W1T   ((size_t)8*3072*768*2)        // bf16 [E][N=3072][K=768]
#define SZ_W2T   ((size_t)8*768*3072*2)        // bf16 [E][N=768][K=3072]
#define SZ_XED   ((size_t)8*8*256*768*2)       // bf16 [E][M=2048][768] det
#define SZ_XEC   ((size_t)8*8*32*768*2)        // cls
#define SZ_HD    ((size_t)8*2048*3072*2)       // bf16 [E][M][3072] det
#define SZ_HC    ((size_t)8*256*3072*2)        // cls
#define SZ_YED   ((size_t)8*2048*768*2)        // bf16 fc2 per-slot out det
#define SZ_YEC   ((size_t)8*256*768*2)         // cls
#define SZ_RID   ((size_t)8192*8)
#define SZ_RGD   ((size_t)8192*8)
#define SZ_RIC   ((size_t)1024*8)
#define SZ_RGC   ((size_t)1024*8)
#define SZ_STD   ((size_t)8*8*256*4)           // slot -> token (det)
#define SZ_STC   ((size_t)8*8*32*4)
#define SZ_TSD   ((size_t)2*8192*4)            // token,rank -> global slot (det)
#define SZ_TSC   ((size_t)2*1024*4)

#define OFF_W1T  ((size_t)0)
#define OFF_W2T  (OFF_W1T + SZ_W1T)
#define OFF_XED  (OFF_W2T + SZ_W2T)
#define OFF_XEC  (OFF_XED + SZ_XED)
#define OFF_HD   (OFF_XEC + SZ_XEC)
#define OFF_HC   (OFF_HD  + SZ_HD)
#define OFF_YED  (OFF_HC  + SZ_HC)
#define OFF_YEC  (OFF_YED + SZ_YED)
#define OFF_RID  (OFF_YEC + SZ_YEC)
#define OFF_RGD  (OFF_RID + SZ_RID)
#define OFF_RIC  (OFF_RGD + SZ_RGD)
#define OFF_RGC  (OFF_RIC + SZ_RIC)
#define OFF_STD  (OFF_RGC + SZ_RGC)
#define OFF_STC  (OFF_STD + SZ_STD)
#define OFF_TSD  (OFF_STC + SZ_STC)
#define OFF_TSC  (OFF_TSD + SZ_TSD)

// ---------------- helpers ------------------------------------------------------
__device__ __forceinline__ void lds_load16(const void* g, void* l) {
  __builtin_amdgcn_global_load_lds((__attribute__((address_space(1))) void*)g,
                                   (__attribute__((address_space(3))) void*)l,
                                   16, 0, 0);
}

// tanh-gelu via the exact identity 0.5*(1+tanh(y)) = sigmoid(2y):
// gelu(x) = x / (1 + exp(z)), z = x*(-1.5957691 - 0.07135481*x^2).
// exp overflow -> +inf -> rcp(1+inf)=0 -> gelu->0 (correct limit, no NaN).
__device__ __forceinline__ float gelu_fast(float x) {
  float x2 = x * x;
  float z = x * __builtin_fmaf(-0.07135481627f, x2, -1.5957691216f);
  float e = __expf(z);
  return x * __builtin_amdgcn_rcpf(1.f + e);
}

// 64x64 fp32->bf16 transpose tile (R4-proven). tile = float[64*65] in LDS.
// 576 tiles per expert for both w1 (768x3072) and w2 (3072x768).
__device__ __forceinline__ void transpose64(const float* __restrict__ src,
                                            bf16* __restrict__ dst,
                                            int K, int N, int e, int t, float* tile) {
  int tiles_x = N >> 6;
  int ky = t / tiles_x;
  int n0 = (t - ky * tiles_x) * 64, k0 = ky * 64;
  const float* S_ = src + (size_t)e * K * N;
  bf16* D_ = dst + (size_t)e * K * N;
  int tid = threadIdx.x;
  int tx = tid & 15, ty = tid >> 4;   // 16 x 16
#pragma unroll
  for (int i = 0; i < 4; ++i) {
    float4 v = *(const float4*)(S_ + (size_t)(k0 + ty + i * 16) * N + (n0 + tx * 4));
    int r = ty + i * 16, c = tx * 4;
    tile[r * 65 + c] = v.x; tile[r * 65 + c + 1] = v.y;
    tile[r * 65 + c + 2] = v.z; tile[r * 65 + c + 3] = v.w;
  }
  __syncthreads();
  int n = tid >> 2, kq = (tid & 3) * 16;
  bf16 o[16];
#pragma unroll
  for (int j = 0; j < 16; ++j) o[j] = (bf16)tile[(kq + j) * 65 + n];
  bf16* drow = D_ + (size_t)(n0 + n) * K + (k0 + kq);
  *(bf16x8*)drow       = *(const bf16x8*)o;
  *(bf16x8*)(drow + 8) = *(const bf16x8*)(o + 8);
}

// ---------------- router (det+cls merged, standalone) --------------------------
__global__ void router_kernel(const float* __restrict__ xd, const float* __restrict__ wrd,
                              const float* __restrict__ xc, const float* __restrict__ wrc,
                              int2* __restrict__ rid, float2* __restrict__ rgd,
                              int2* __restrict__ ric, float2* __restrict__ rgc,
                              int splitd) {
  int bid = blockIdx.x;
  const float *x, *wr; int2* ridx; float2* rgate;
  if (bid < splitd) { x = xd; wr = wrd; ridx = rid; rgate = rgd; }
  else { bid -= splitd; x = xc; wr = wrc; ridx = ric; rgate = rgc; }
  int wave = threadIdx.x >> 6;
  int lane = threadIdx.x & 63;
  int t = bid * 4 + wave;
  const float* xr = x + (size_t)t * D_MODEL;
  float acc[8];
#pragma unroll
  for (int e = 0; e < 8; ++e) acc[e] = 0.f;
  for (int d = lane; d < D_MODEL; d += 64) {
    float xv = xr[d];
    const float* w = wr + d * 8;
    float4 a = *(const float4*)w;
    float4 b = *(const float4*)(w + 4);
    acc[0] += xv * a.x; acc[1] += xv * a.y; acc[2] += xv * a.z; acc[3] += xv * a.w;
    acc[4] += xv * b.x; acc[5] += xv * b.y; acc[6] += xv * b.z; acc[7] += xv * b.w;
  }
#pragma unroll
  for (int off = 32; off > 0; off >>= 1) {
#pragma unroll
    for (int e = 0; e < 8; ++e) acc[e] += __shfl_xor(acc[e], off, 64);
  }
  float mx = acc[0];
#pragma unroll
  for (int e = 1; e < 8; ++e) mx = fmaxf(mx, acc[e]);
  float p[8]; float z = 0.f;
#pragma unroll
  for (int e = 0; e < 8; ++e) { p[e] = __expf(acc[e] - mx); z += p[e]; }
  int i1 = 0;
#pragma unroll
  for (int e = 1; e < 8; ++e) if (p[e] > p[i1]) i1 = e;
  int i2 = (i1 == 0) ? 1 : 0;
#pragma unroll
  for (int e = 0; e < 8; ++e) if (e != i1 && p[e] > p[i2]) i2 = e;
  if (lane == 0) {
    float inv = 1.f / z;
    ridx[t]  = make_int2(i1, i2);
    rgate[t] = make_float2(p[i1] * inv, p[i2] * inv);
  }
}

// ---------------- capacity positions + inverse map (det+cls merged) ------------
__global__ void positions_kernel(const int2* __restrict__ rid, int* __restrict__ std_,
                                 int* __restrict__ tsd_, const int2* __restrict__ ric,
                                 int* __restrict__ stc_, int* __restrict__ tsc_) {
  __shared__ int2 sh[1024];
  int bid = blockIdx.x;
  const int2* ridx; int *slot_token, *tok_slot; int S, C, g;
  if (bid < 8) { ridx = rid; slot_token = std_; tok_slot = tsd_; S = 1024; C = 256; g = bid; }
  else { ridx = ric; slot_token = stc_; tok_slot = tsc_; S = 128; C = 32; g = bid - 8; }
  int lane = threadIdx.x;
  int ntok = 8 * S;
  for (int i = lane; i < S; i += 64) sh[i] = ridx[g * S + i];
  __builtin_amdgcn_s_waitcnt(0);   // single wave: no barrier needed
  unsigned long long ltmask = (1ull << lane) - 1ull;
  int cnt[8];
#pragma unroll
  for (int e = 0; e < 8; ++e) cnt[e] = 0;
  int nch = (2 * S) >> 6;
  for (int ch = 0; ch < nch; ++ch) {
    int a = (ch << 6) + lane;
    int r = (a >= S) ? 1 : 0;
    int s = a - r * S;
    int2 id = sh[s];
    int  e  = r ? id.y : id.x;
    unsigned long long mymask = 0;
    int add[8];
#pragma unroll
    for (int ee = 0; ee < 8; ++ee) {
      unsigned long long mk = __ballot(e == ee);
      if (e == ee) mymask = mk;
      add[ee] = __popcll(mk);
    }
    int pos = cnt[e] + __popcll(mymask & ltmask);
    int sl = (e * 8 + g) * C + pos;       // global slot id == e*M + (g*C+pos)
    if (pos < C) slot_token[sl] = s;
    tok_slot[r * ntok + g * S + s] = (pos < C) ? sl : -1;
#pragma unroll
    for (int ee = 0; ee < 8; ++ee) cnt[ee] += add[ee];
  }
  // back-fill unused slots with -1 (replaces the memset kernel)
#pragma unroll
  for (int e = 0; e < 8; ++e) {
    for (int i = cnt[e] + lane; i < C; i += 64)
      slot_token[(e * 8 + g) * C + i] = -1;
  }
}

// ---------------- gather + w1 transpose merged ---------------------------------
// bids [0, nT): w1 transpose (long pole first); bids [nT, ...): gather det+cls.
// w1t is consumed by fc1 which launches after this kernel -> ordering free.
__global__ void gather_w1t_kernel(const float* __restrict__ xd, const int* __restrict__ std_,
                                  bf16* __restrict__ xed, const float* __restrict__ xc,
                                  const int* __restrict__ stc_, bf16* __restrict__ xec,
                                  int splitd, const float* __restrict__ w1,
                                  bf16* __restrict__ w1t, int nT) {
  __shared__ float tile[64 * 65];
  int bid = blockIdx.x;
  if (bid < nT) {
    int e = bid / 576;
    int t = bid - e * 576;
    transpose64(w1, w1t, 768, 3072, e, t, tile);
    return;
  }
  bid -= nT;
  const float* x; const int* slot_token; bf16* xe; int S, C;
  if (bid < splitd) { x = xd; slot_token = std_; xe = xed; S = 1024; C = 256; }
  else { bid -= splitd; x = xc; slot_token = stc_; xe = xec; S = 128; C = 32; }
  int slot = bid * 4 + (threadIdx.x >> 6);
  int lane = threadIdx.x & 63;
  int g = (slot / C) & 7;
  int s = slot_token[slot];
  bf16* dst = xe + (size_t)slot * D_MODEL;
  const float* xr = x + ((size_t)g * S + (s < 0 ? 0 : s)) * D_MODEL;
#pragma unroll
  for (int j = 0; j < 3; ++j) {
    int idx = j * 256 + lane * 4;
    float4 v;
    if (s >= 0) v = *(const float4*)(xr + idx);
    else        v = make_float4(0.f, 0.f, 0.f, 0.f);
    bf16 o[4] = {(bf16)v.x, (bf16)v.y, (bf16)v.z, (bf16)v.w};
    *(uint2*)(dst + idx) = *(const uint2*)o;
  }
}

// ---------------- combine (det+cls merged): 4 tokens per block -----------------
__global__ void combine_kernel(const int* __restrict__ tsd_, const float2* __restrict__ rgd,
                               const bf16* __restrict__ yed, float* __restrict__ outd,
                               const int* __restrict__ tsc_, const float2* __restrict__ rgc,
                               const bf16* __restrict__ yec, float* __restrict__ outc,
                               int splitd) {
  int bid = blockIdx.x;
  const int* tok_slot; const float2* rgate; const bf16* ye; float* out; int ntok;
  if (bid < splitd) { tok_slot = tsd_; rgate = rgd; ye = yed; out = outd; ntok = 8192; }
  else { bid -= splitd; tok_slot = tsc_; rgate = rgc; ye = yec; out = outc; ntok = 1024; }
  int t = bid * 4 + (threadIdx.x >> 6);
  int lane = threadIdx.x & 63;
  int s1 = tok_slot[t];
  int s2 = tok_slot[ntok + t];
  float2 gg = rgate[t];
  float g1 = (s1 < 0) ? 0.f : gg.x;
  float g2 = (s2 < 0) ? 0.f : gg.y;
  const bf16* y1 = ye + (size_t)(s1 < 0 ? 0 : s1) * D_MODEL;
  const bf16* y2 = ye + (size_t)(s2 < 0 ? 0 : s2) * D_MODEL;
  float* orow = out + (size_t)t * D_MODEL;
#pragma unroll
  for (int j = 0; j < 3; ++j) {
    int idx = j * 256 + lane * 4;
    bf16x4 a = *(const bf16x4*)(y1 + idx);
    bf16x4 b = *(const bf16x4*)(y2 + idx);
    float4 o;
    o.x = g1 * (float)a[0] + g2 * (float)b[0];
    o.y = g1 * (float)a[1] + g2 * (float)b[1];
    o.z = g1 * (float)a[2] + g2 * (float)b[2];
    o.w = g1 * (float)a[3] + g2 * (float)b[3];
    *(float4*)(orow + idx) = o;
  }
}

// ---------------- 128x128 bf16 MFMA GEMM + trailing w2-transpose blocks --------
// EXACT R0 GEMM structure (runtime K, VGPR=64+64acc, 3 blocks/CU) for fc1
// (nt=12). bids >= nGemm run the w2 transpose (w2t needed only by fc2): fc1 is
// compute-bound at 23% HBM, so the transpose's ~113MB (~18us BW) hides in fc1's
// tail. Disjoint top-level branch -- GEMM regalloc unchanged (check VGPR=64).
template <int GELU>
__launch_bounds__(256, 3)
__global__ void gemm_mfma(const bf16* __restrict__ Adet, const bf16* __restrict__ Acls,
                          const bf16* __restrict__ Btall, const float* __restrict__ biasall,
                          int Mdet, int Mcls, int N, int K,
                          int Nmd, int Nmc, int Nn, int minner, int splitd,
                          bf16* __restrict__ Odet, bf16* __restrict__ Ocls,
                          const float* __restrict__ tsrc, bf16* __restrict__ tdst,
                          int nGemm) {
  // 32 KB: K-loop A(16KB)|B(16KB); epilogue reuses all 32 KB as 128x128 C-tile;
  // transpose path reuses first 16.6 KB as float[64][65].
  __shared__ __align__(16) bf16 smem[16384];

  int bid = blockIdx.x;
  if (bid >= nGemm) {
    int t2 = bid - nGemm;
    int e = t2 / 576;
    int t = t2 - e * 576;
    transpose64(tsrc, tdst, 3072, 768, e, t, (float*)smem);
    return;
  }

  const bf16* Aall; bf16* Oall; int M, Nm;
  if (bid < splitd) { Aall = Adet; Oall = Odet; M = Mdet; Nm = Nmd; }
  else { bid -= splitd; Aall = Acls; Oall = Ocls; M = Mcls; Nm = Nmc; }
  const int e   = bid & 7;                 // expert == XCD (blockIdx%8 heuristic)
  const int seq = bid >> 3;
  int m_t, n_t;
  if (minner) { n_t = seq / Nm; m_t = seq - n_t * Nm; }   // fc1: A_e resident in L2
  else        { m_t = seq / Nn; n_t = seq - m_t * Nn; }
  const int n0 = n_t * 128;
  const int m0 = m_t * 128;
  const int tid  = threadIdx.x;
  const int wave = tid >> 6, lane = tid & 63;
  const int wm = (wave >> 1) * 64, wn = (wave & 1) * 64;
  const int lrow = lane & 15, lquad = lane >> 4;

  bf16* As = smem;
  bf16* Bs = smem + 8192;

  const bf16* A  = Aall  + (size_t)e * M * K;
  const bf16* Bt = Btall + (size_t)e * N * K;

  // staging: 4 rounds x 32 rows x 8 chunks(16B) per 16KB tile
  const int srow = tid >> 3;                         // 0..31
  const int gq   = (tid & 7) ^ (srow & 7);           // global chunk (swizzled)
  const bf16* Asrc = A  + (size_t)(m0 + srow) * K + gq * 8;
  const bf16* Bsrc = Bt + (size_t)(n0 + srow) * K + gq * 8;
  char* AsB = (char*)As;
  char* BsB = (char*)Bs;
  const int ldsw = wave * 1024;                      // wave-uniform (+lane*16 HW)

  // bias fragment (4 cols per lane)
  const float* bias = biasall + (size_t)e * N;
  float bfr[4];
#pragma unroll
  for (int ni = 0; ni < 4; ++ni) bfr[ni] = bias[n0 + wn + ni * 16 + lrow];

  f32x4 acc[4][4];
#pragma unroll
  for (int mi = 0; mi < 4; ++mi)
#pragma unroll
    for (int ni = 0; ni < 4; ++ni) acc[mi][ni] = {0.f, 0.f, 0.f, 0.f};

  const int xsw = lrow & 7;                          // fragment chunk de-swizzle
  const int nsteps = K >> 6;
  for (int kt = 0; kt < nsteps; ++kt) {
    const bf16* a0 = Asrc + kt * 64;
    const bf16* b0 = Bsrc + kt * 64;
#pragma unroll
    for (int rd = 0; rd < 4; ++rd) {
      lds_load16(a0 + (size_t)(rd * 32) * K, AsB + rd * 4096 + ldsw);
      lds_load16(b0 + (size_t)(rd * 32) * K, BsB + rd * 4096 + ldsw);
    }
    __syncthreads();
#pragma unroll
    for (int h = 0; h < 2; ++h) {
      bf16x8 fa[4], fb[4];
      const int ca = ((h * 4 + lquad) ^ xsw) * 8;
#pragma unroll
      for (int i = 0; i < 4; ++i) {
        fa[i] = *(const bf16x8*)(As + (wm + i * 16 + lrow) * 64 + ca);
        fb[i] = *(const bf16x8*)(Bs + (wn + i * 16 + lrow) * 64 + ca);
      }
#pragma unroll
      for (int mi = 0; mi < 4; ++mi)
#pragma unroll
        for (int ni = 0; ni < 4; ++ni)
          acc[mi][ni] = __builtin_amdgcn_mfma_f32_16x16x32_bf16(fa[mi], fb[ni], acc[mi][ni], 0, 0, 0);
    }
    __syncthreads();
  }

  // ---- epilogue: acc -> LDS (swizzled) -> coalesced b128 global stores --------
#pragma unroll
  for (int mi = 0; mi < 4; ++mi) {
#pragma unroll
    for (int r = 0; r < 4; ++r) {
      int row = wm + mi * 16 + lquad * 4 + r;
#pragma unroll
      for (int ni = 0; ni < 4; ++ni) {
        int colL = wn + ni * 16 + lrow;
        float v = acc[mi][ni][r] + bfr[ni];
        if (GELU) v = gelu_fast(v);
        int chunk = (colL >> 3) ^ (row & 7);           // 16B-chunk swizzle
        smem[row * 128 + chunk * 8 + (colL & 7)] = (bf16)v;
      }
    }
  }
  __syncthreads();
  bf16* O = Oall + (size_t)e * M * N;
#pragma unroll
  for (int it = 0; it < 8; ++it) {
    int idx = it * 256 + tid;          // 0..2047
    int row = idx >> 4;                // 0..127
    int ck  = idx & 15;
    int pchunk = ck ^ (row & 7);
    bf16x8 vv = *(const bf16x8*)(smem + row * 128 + pchunk * 8);
    *(bf16x8*)(O + (size_t)(m0 + row) * N + n0 + ck * 8) = vv;
  }
}

// ---------------- 256x256 bf16 MFMA GEMM, 8-phase counted-vmcnt (fc2 only) -----
// R5-proven: fc2's nt=48 amortizes the pipeline prologue; counted vmcnt(4)
// keeps loads in flight across barriers. -22.5us vs 128^2 (R4->R5 A/B).
template <int GELU>
__launch_bounds__(512, 2)
__global__ void gemm_mfma8p(const bf16* __restrict__ Adet, const bf16* __restrict__ Acls,
                            const bf16* __restrict__ Btall, const float* __restrict__ biasall,
                            int Mdet, int Mcls, int N, int K,
                            int Nmd, int Nmc, int Nn, int minner, int splitd,
                            bf16* __restrict__ Odet, bf16* __restrict__ Ocls) {
  int bid = blockIdx.x;
  const bf16* Aall; bf16* Oall; int M, Nm;
  if (bid < splitd) { Aall = Adet; Oall = Odet; M = Mdet; Nm = Nmd; }
  else { bid -= splitd; Aall = Acls; Oall = Ocls; M = Mcls; Nm = Nmc; }
  const int e   = bid & 7;
  const int seq = bid >> 3;
  int m_t, n_t;
  if (minner) { n_t = seq / Nm; m_t = seq - n_t * Nm; }
  else        { m_t = seq / Nn; n_t = seq - m_t * Nn; }
  const int n0 = n_t * 256;
  const int m0 = m_t * 256;
  const int tid  = threadIdx.x;
  const int wave = tid >> 6, lane = tid & 63;
  const int wm = (wave >> 2) * 128, wn = (wave & 3) * 64;
  const int lrow = lane & 15, lquad = lane >> 4;

  __shared__ __align__(16) bf16 smem[65536];
  char* smemB = (char*)smem;

  const bf16* A  = Aall  + (size_t)e * M * K;
  const bf16* Bt = Btall + (size_t)e * N * K;

  const int srow0 = tid >> 3;                        // 0..63
  const int gq    = (tid & 7) ^ (srow0 & 7);
  const bf16* Asrc = A  + (size_t)(m0 + srow0) * K + gq * 8;
  const bf16* Bsrc = Bt + (size_t)(n0 + srow0) * K + gq * 8;
  const int ldsw = wave * 1024;

  const int aBase = (wm ? 8192 : 0) + lrow * 64;
  const int bBase = 16384 + (wn >= 128 ? 8192 : 0) + (wn & 64) * 64 + lrow * 64;
  const int ca0 = (lquad ^ (lrow & 7)) * 8;
  const int ca1 = ca0 ^ 32;

  const float* bias = biasall + (size_t)e * N;
  float bfr[4];
#pragma unroll
  for (int ni = 0; ni < 4; ++ni) bfr[ni] = bias[n0 + wn + ni * 16 + lrow];

  f32x4 acc[8][4];
#pragma unroll
  for (int mi = 0; mi < 8; ++mi)
#pragma unroll
    for (int ni = 0; ni < 4; ++ni) acc[mi][ni] = {0.f, 0.f, 0.f, 0.f};

  bf16x8 fa[2][4], fb0[2][2], fb1[2][2];

#define STG_A(buf, half, kt) do { \
    const bf16* _s = Asrc + (size_t)((half) * 128) * K + (size_t)(kt) * 64; \
    char* _d = smemB + (buf) * 65536 + (half) * 16384 + ldsw; \
    lds_load16(_s, _d); \
    lds_load16(_s + (size_t)64 * K, _d + 8192); \
  } while (0)
#define STG_B(buf, half, kt) do { \
    const bf16* _s = Bsrc + (size_t)((half) * 128) * K + (size_t)(kt) * 64; \
    char* _d = smemB + (buf) * 65536 + 32768 + (half) * 16384 + ldsw; \
    lds_load16(_s, _d); \
    lds_load16(_s + (size_t)64 * K, _d + 8192); \
  } while (0)
#define LDA(buf, qm) do { \
    const bf16* _p = smem + (buf) * 32768 + aBase + (qm) * 4096; \
    _Pragma("unroll") \
    for (int _i = 0; _i < 4; ++_i) { \
      fa[0][_i] = *(const bf16x8*)(_p + _i * 1024 + ca0); \
      fa[1][_i] = *(const bf16x8*)(_p + _i * 1024 + ca1); \
    } \
  } while (0)
#define LDB(buf, qn, FB) do { \
    const bf16* _p = smem + (buf) * 32768 + bBase + (qn) * 2048; \
    _Pragma("unroll") \
    for (int _j = 0; _j < 2; ++_j) { \
      FB[0][_j] = *(const bf16x8*)(_p + _j * 1024 + ca0); \
      FB[1][_j] = *(const bf16x8*)(_p + _j * 1024 + ca1); \
    } \
  } while (0)
#define MM(qm, qn, FB) do { \
    __builtin_amdgcn_s_setprio(1); \
    _Pragma("unroll") \
    for (int _h = 0; _h < 2; ++_h) \
      _Pragma("unroll") \
      for (int _i = 0; _i < 4; ++_i) \
        _Pragma("unroll") \
        for (int _j = 0; _j < 2; ++_j) \
          acc[(qm) * 4 + _i][(qn) * 2 + _j] = __builtin_amdgcn_mfma_f32_16x16x32_bf16( \
              fa[_h][_i], FB[_h][_j], acc[(qm) * 4 + _i][(qn) * 2 + _j], 0, 0, 0); \
    __builtin_amdgcn_s_setprio(0); \
  } while (0)
#define BAR() __builtin_amdgcn_s_barrier()
#define VMC4() asm volatile("s_waitcnt vmcnt(4)" ::: "memory")

  const int nt = K >> 6;          // 48 for fc2; even
  const int niter = nt >> 1;

  // prologue: buf0 <- K0 (4 halves), buf1 <- K1 B-halves; wait buf0 only.
  STG_B(0, 0, 0); STG_B(0, 1, 0); STG_A(0, 0, 0); STG_A(0, 1, 0);
  STG_B(1, 0, 1); STG_B(1, 1, 1);
  VMC4();
  BAR();

  for (int it = 0; it < niter; ++it) {
    const int k1 = 2 * it + 1;
    const int k2 = (2 * it + 2 < nt) ? 2 * it + 2 : nt - 1;   // clamp tail
    const int k3 = (2 * it + 3 < nt) ? 2 * it + 3 : nt - 1;
    // ---- K-tile 2it (buf0) ----
    LDA(0, 0); LDB(0, 0, fb0); STG_A(1, 0, k1); BAR(); MM(0, 0, fb0); BAR();  // P1
    LDB(0, 1, fb1);            STG_A(1, 1, k1); BAR(); MM(0, 1, fb1); BAR();  // P2
    LDA(0, 1);                 STG_B(0, 0, k2); BAR(); MM(1, 1, fb1); BAR();  // P3
                               STG_B(0, 1, k2); VMC4();
                                                BAR(); MM(1, 0, fb0); BAR();  // P4
    // ---- K-tile 2it+1 (buf1) ----
    LDA(1, 0); LDB(1, 0, fb0); STG_A(0, 0, k2); BAR(); MM(0, 0, fb0); BAR();  // P5
    LDB(1, 1, fb1);            STG_A(0, 1, k2); BAR(); MM(0, 1, fb1); BAR();  // P6
    LDA(1, 1);                 STG_B(1, 0, k3); BAR(); MM(1, 1, fb1); BAR();  // P7
                               STG_B(1, 1, k3); VMC4();
                                                BAR(); MM(1, 0, fb0); BAR();  // P8
  }

#undef STG_A
#undef STG_B
#undef LDA
#undef LDB
#undef MM
#undef BAR
#undef VMC4

  // ---- epilogue: acc -> LDS (swizzled 256x256 C-tile) -> coalesced b128 stores
  __syncthreads();   // drains leftover tail stages before smem reuse
#pragma unroll
  for (int mi = 0; mi < 8; ++mi) {
#pragma unroll
    for (int r = 0; r < 4; ++r) {
      int row = wm + mi * 16 + lquad * 4 + r;
#pragma unroll
      for (int ni = 0; ni < 4; ++ni) {
        int colL = wn + ni * 16 + lrow;
        float v = acc[mi][ni][r] + bfr[ni];
        if (GELU) v = gelu_fast(v);
        int chunk = (colL >> 3) ^ (row & 7);           // 16B-chunk swizzle
        smem[row * 256 + chunk * 8 + (colL & 7)] = (bf16)v;
      }
    }
  }
  __syncthreads();
  bf16* O = Oall + (size_t)e * M * N;
#pragma unroll
  for (int itw = 0; itw < 16; ++itw) {
    int idx = itw * 512 + tid;         // 0..8191
    int row = idx >> 5;                // 0..255
    int ck  = idx & 31;
    int pchunk = ck ^ (row & 7);
    bf16x8 vv = *(const bf16x8*)(smem + row * 256 + pchunk * 8);
    *(bf16x8*)(O + (size_t)(m0 + row) * N + n0 + ck * 8) = vv;
  }
}

// ---------------- launch -------------------------------------------------------
extern "C" void kernel_launch(void* const* d_in, const int* in_sizes, int n_in,
                              void* d_out, int out_size, void* d_ws, size_t ws_size,
                              hipStream_t stream) {
  (void)in_sizes; (void)n_in; (void)ws_size; (void)out_size;
  const float* x_det  = (const float*)d_in[0];
  const float* x_cls  = (const float*)d_in[1];
  const float* wr_det = (const float*)d_in[2];
  const float* wr_cls = (const float*)d_in[3];
  const float* w1     = (const float*)d_in[4];
  const float* b1     = (const float*)d_in[5];
  const float* w2     = (const float*)d_in[6];
  const float* b2     = (const float*)d_in[7];
  float* out = (float*)d_out;
  char*  ws  = (char*)d_ws;

  bf16*   w1t    = (bf16*)(ws + OFF_W1T);
  bf16*   w2t    = (bf16*)(ws + OFF_W2T);
  bf16*   xe_det = (bf16*)(ws + OFF_XED);
  bf16*   xe_cls = (bf16*)(ws + OFF_XEC);
  bf16*   h_det  = (bf16*)(ws + OFF_HD);
  bf16*   h_cls  = (bf16*)(ws + OFF_HC);
  bf16*   ye_det = (bf16*)(ws + OFF_YED);
  bf16*   ye_cls = (bf16*)(ws + OFF_YEC);
  int2*   ri_det = (int2*)(ws + OFF_RID);
  float2* rg_det = (float2*)(ws + OFF_RGD);
  int2*   ri_cls = (int2*)(ws + OFF_RIC);
  float2* rg_cls = (float2*)(ws + OFF_RGC);
  int*    st_det = (int*)(ws + OFF_STD);
  int*    st_cls = (int*)(ws + OFF_STC);
  int*    ts_det = (int*)(ws + OFF_TSD);
  int*    ts_cls = (int*)(ws + OFF_TSC);

  // routing (standalone; transpose work moved into gather/fc1 launches)
  router_kernel<<<2048 + 256, 256, 0, stream>>>(x_det, wr_det, x_cls, wr_cls,
                                                ri_det, rg_det, ri_cls, rg_cls, 2048);

  positions_kernel<<<16, 64, 0, stream>>>(ri_det, st_det, ts_det, ri_cls, st_cls, ts_cls);

  // gather + w1 transpose (w1t ready before fc1; transpose bids first)
  gather_w1t_kernel<<<4608 + 4096 + 512, 256, 0, stream>>>(
      x_det, st_det, xe_det, x_cls, st_cls, xe_cls, 4096, w1, w1t, 4608);

  // fc1 + w2 transpose: h = gelu(xe @ w1 + b1); 128^2 2-barrier (nt=12);
  // trailing 4608 blocks transpose w2 (ready before fc2)
  gemm_mfma<1><<<8 * 16 * 24 + 8 * 2 * 24 + 4608, 256, 0, stream>>>(
      xe_det, xe_cls, w1t, b1, 2048, 256, 3072, 768,
      16, 2, 24, 1, 8 * 16 * 24, h_det, h_cls, w2, w2t, 3456);

  // fc2 (det+cls merged): ye = h @ w2 + b2; 256^2 8-phase (nt=48)
  gemm_mfma8p<0><<<8 * 8 * 3 + 8 * 1 * 3, 512, 0, stream>>>(
      h_det, h_cls, w2t, b2, 2048, 256, 768, 3072,
      8, 1, 3, 0, 8 * 8 * 3, ye_det, ye_cls);

  // combine (det+cls merged): out[t] = sum_r gate_r * ye[slot_r]
  combine_kernel<<<2048 + 256, 256, 0, stream>>>(ts_det, rg_det, ye_det, out,
                                                 ts_cls, rg_cls, ye_cls,
                                                 out + (size_t)8192 * 768, 2048);
}